// Round 4
// baseline (3300.439 us; speedup 1.0000x reference)
//
#include <hip/hip_runtime.h>
#include <hip/hip_bf16.h>
#include <cstdint>

#define B_ 2
#define S_ 2048
#define D_ 1024
#define H_ 16
#define HKV_ 4
#define HD_ 64
#define E_ 8
#define HIDDEN_ 684
#define NT_ (B_*S_)   // 4096 tokens
#define NEGBIG (-1e30f)

using bf16 = __hip_bfloat16;

static __device__ __forceinline__ float b2f(bf16 v){ return __bfloat162float(v); }
static __device__ __forceinline__ bf16 f2b(float v){ return __float2bfloat16(v); }
static __device__ __forceinline__ float ldf(float v){ return v; }
static __device__ __forceinline__ float ldf(bf16 v){ return __bfloat162float(v); }

// Detect device float dtype from g_attn == ones(1024).
// bf16 ones -> dwords 0x3F803F80 ; fp32 ones -> 0x3F800000. flag=1 => bf16.
__global__ void k_detect(const uint32_t* __restrict__ g, int* __restrict__ flag, int* __restrict__ cnt){
  if(threadIdx.x == 0 && blockIdx.x == 0){
    uint32_t w0 = g[0], w1 = g[1], w2 = g[2], w3 = g[3];
    int bf;
    if(w0==0x3F803F80u && w1==0x3F803F80u && w2==0x3F803F80u && w3==0x3F803F80u) bf = 1;
    else if(w0==0x3F800000u && w1==0x3F800000u && w2==0x3F800000u && w3==0x3F800000u) bf = 0;
    else bf = 1;
    flag[0] = bf;
  }
  if(threadIdx.x < E_ && blockIdx.x == 0) cnt[threadIdx.x] = 0;
}

// ---------------- RMSNorm -> f32 out ----------------
template<typename TX, typename TG>
__global__ __launch_bounds__(256) void k_rms(const TX* __restrict__ X, const TG* __restrict__ g,
                                             float* __restrict__ out, const int* __restrict__ flag, int want){
  if(flag[0] != want) return;
  int t = blockIdx.x; int tid = threadIdx.x;
  const TX* xr = X + (size_t)t*D_;
  float v[4]; float ss = 0.f;
  #pragma unroll
  for(int i=0;i<4;i++){ v[i] = ldf(xr[tid + i*256]); ss += v[i]*v[i]; }
  __shared__ float red[256];
  red[tid] = ss; __syncthreads();
  for(int st=128; st>0; st>>=1){ if(tid<st) red[tid] += red[tid+st]; __syncthreads(); }
  float r = rsqrtf(red[0]*(1.f/(float)D_) + 1e-5f);
  #pragma unroll
  for(int i=0;i<4;i++){
    int d = tid + i*256;
    out[(size_t)t*D_ + d] = v[i]*r*ldf(g[d]);
  }
}

// ---------------- GEMM: C(f32)[M,N] = A(f32)[M,K] @ B[K,N] ----------------
template<typename TB>
__global__ __launch_bounds__(256) void k_gemm(const float* __restrict__ A, const TB* __restrict__ Bm,
                                              float* __restrict__ C, int M, int N, int K,
                                              const int* __restrict__ flag, int want){
  if(flag[0] != want) return;
  __shared__ float As[64][17];
  __shared__ float Bs[16][65];
  int m0 = blockIdx.y*64, n0 = blockIdx.x*64;
  int tid = threadIdx.x; int tx = tid&15, ty = tid>>4;
  float acc[4][4] = {};
  for(int k0=0;k0<K;k0+=16){
    __syncthreads();
    #pragma unroll
    for(int p=0;p<4;p++){ int idx = tid + p*256; int r = idx>>4, c = idx&15;
      int gm = m0+r, gk = k0+c;
      As[r][c] = (gm<M && gk<K) ? A[(size_t)gm*K+gk] : 0.f; }
    #pragma unroll
    for(int p=0;p<4;p++){ int idx = tid + p*256; int r = idx>>6, c = idx&63;
      int gk = k0+r, gn = n0+c;
      Bs[r][c] = (gk<K && gn<N) ? ldf(Bm[(size_t)gk*N+gn]) : 0.f; }
    __syncthreads();
    #pragma unroll
    for(int kk=0;kk<16;kk++){
      float a[4], b[4];
      #pragma unroll
      for(int i=0;i<4;i++) a[i] = As[ty*4+i][kk];
      #pragma unroll
      for(int j=0;j<4;j++) b[j] = Bs[kk][tx*4+j];
      #pragma unroll
      for(int i=0;i<4;i++)
        #pragma unroll
        for(int j=0;j<4;j++) acc[i][j] += a[i]*b[j];
    }
  }
  #pragma unroll
  for(int i=0;i<4;i++){ int gm = m0+ty*4+i; if(gm>=M) continue;
    #pragma unroll
    for(int j=0;j<4;j++){ int gn = n0+tx*4+j; if(gn<N) C[(size_t)gm*N+gn] = acc[i][j]; } }
}

// GEMM + residual: C(f32) = A(f32)@B + resid
template<typename TE>
__global__ __launch_bounds__(256) void k_gemm_resid(const float* __restrict__ A, const TE* __restrict__ Bm,
                                                    const TE* __restrict__ resid, float* __restrict__ C,
                                                    int M, int N, int K,
                                                    const int* __restrict__ flag, int want){
  if(flag[0] != want) return;
  __shared__ float As[64][17];
  __shared__ float Bs[16][65];
  int m0 = blockIdx.y*64, n0 = blockIdx.x*64;
  int tid = threadIdx.x; int tx = tid&15, ty = tid>>4;
  float acc[4][4] = {};
  for(int k0=0;k0<K;k0+=16){
    __syncthreads();
    #pragma unroll
    for(int p=0;p<4;p++){ int idx = tid + p*256; int r = idx>>4, c = idx&15;
      int gm = m0+r, gk = k0+c;
      As[r][c] = (gm<M && gk<K) ? A[(size_t)gm*K+gk] : 0.f; }
    #pragma unroll
    for(int p=0;p<4;p++){ int idx = tid + p*256; int r = idx>>6, c = idx&63;
      int gk = k0+r, gn = n0+c;
      Bs[r][c] = (gk<K && gn<N) ? ldf(Bm[(size_t)gk*N+gn]) : 0.f; }
    __syncthreads();
    #pragma unroll
    for(int kk=0;kk<16;kk++){
      float a[4], b[4];
      #pragma unroll
      for(int i=0;i<4;i++) a[i] = As[ty*4+i][kk];
      #pragma unroll
      for(int j=0;j<4;j++) b[j] = Bs[kk][tx*4+j];
      #pragma unroll
      for(int i=0;i<4;i++)
        #pragma unroll
        for(int j=0;j<4;j++) acc[i][j] += a[i]*b[j];
    }
  }
  #pragma unroll
  for(int i=0;i<4;i++){ int gm = m0+ty*4+i; if(gm>=M) continue;
    #pragma unroll
    for(int j=0;j<4;j++){ int gn = n0+tx*4+j; if(gn<N)
      C[(size_t)gm*N+gn] = acc[i][j] + ldf(resid[(size_t)gm*N+gn]); } }
}

// ---------------- RoPE in-place on q (4096x1024) and k (4096x256), f32 ----------------
template<typename TF>
__global__ __launch_bounds__(256) void k_rope(float* __restrict__ ql, float* __restrict__ kl,
                                              const TF* __restrict__ fc, const TF* __restrict__ fs,
                                              const int* __restrict__ flag, int want){
  if(flag[0] != want) return;
  int t = blockIdx.x; int s = t % S_;
  int tid = threadIdx.x;
  // q: 16 heads x 32 pairs = 512 pairs
  for(int p0 = tid; p0 < 512; p0 += 256){
    int h = p0>>5, p = p0&31;
    float c = ldf(fc[s*32+p]), sn = ldf(fs[s*32+p]);
    size_t o = (size_t)t*D_ + h*64 + 2*p;
    float xr = ql[o], xi = ql[o+1];
    ql[o]   = xr*c - xi*sn;
    ql[o+1] = xr*sn + xi*c;
  }
  // k: 4 heads x 32 pairs = 128 pairs
  if(tid < 128){
    int h = tid>>5, p = tid&31;
    float c = ldf(fc[s*32+p]), sn = ldf(fs[s*32+p]);
    size_t o = (size_t)t*256 + h*64 + 2*p;
    float xr = kl[o], xi = kl[o+1];
    kl[o]   = xr*c - xi*sn;
    kl[o+1] = xr*sn + xi*c;
  }
}

// ---------------- Flash attention, f32 in / f32 out, strided [t, h*64+d] reads ----------------
__global__ __launch_bounds__(256) void k_attn(const float* __restrict__ Q, const float* __restrict__ Kg,
                                              const float* __restrict__ V, float* __restrict__ Out){
  int qt_ = (S_/64 - 1) - blockIdx.x;
  int h = blockIdx.y, b = blockIdx.z;
  int kvh = h>>2;
  const float* qb = Q + (size_t)b*S_*D_ + (size_t)h*HD_;            // row stride D_
  const float* kb = Kg + (size_t)b*S_*(HKV_*HD_) + (size_t)kvh*HD_; // row stride 256
  const float* vb = V  + (size_t)b*S_*(HKV_*HD_) + (size_t)kvh*HD_;
  __shared__ float Qs[64][65];
  __shared__ float Ks[64][65];   // reused as P after scores consumed
  __shared__ float Vs[64][65];
  float (*Ps)[65] = Ks;
  int tid = threadIdx.x, tx = tid&15, ty = tid>>4;
  #pragma unroll
  for(int p=0;p<16;p++){ int idx = tid + p*256; int r = idx>>6, d = idx&63;
    Qs[r][d] = qb[(size_t)(qt_*64+r)*D_ + d] * 0.125f; }
  float m[4], l[4], acc[4][4] = {};
  #pragma unroll
  for(int i=0;i<4;i++){ m[i] = NEGBIG; l[i] = 0.f; }
  for(int kt=0; kt<=qt_; kt++){
    __syncthreads();
    #pragma unroll
    for(int p=0;p<16;p++){ int idx = tid + p*256; int r = idx>>6, d = idx&63;
      Ks[r][d] = kb[(size_t)(kt*64+r)*256 + d];
      Vs[r][d] = vb[(size_t)(kt*64+r)*256 + d]; }
    __syncthreads();
    float s[4][4] = {};
    for(int d=0; d<64; d++){
      float a[4], bb[4];
      #pragma unroll
      for(int i=0;i<4;i++) a[i] = Qs[ty*4+i][d];
      #pragma unroll
      for(int j=0;j<4;j++) bb[j] = Ks[tx*4+j][d];
      #pragma unroll
      for(int i=0;i<4;i++)
        #pragma unroll
        for(int j=0;j<4;j++) s[i][j] += a[i]*bb[j];
    }
    if(kt == qt_){
      #pragma unroll
      for(int i=0;i<4;i++)
        #pragma unroll
        for(int j=0;j<4;j++) if(tx*4+j > ty*4+i) s[i][j] = NEGBIG;
    }
    float pkeep[4][4];
    #pragma unroll
    for(int i=0;i<4;i++){
      float mx = fmaxf(fmaxf(s[i][0],s[i][1]), fmaxf(s[i][2],s[i][3]));
      for(int msk=1;msk<16;msk<<=1) mx = fmaxf(mx, __shfl_xor(mx, msk, 64));
      float mn = fmaxf(m[i], mx);
      float sc = expf(m[i]-mn);
      float ps = 0.f;
      #pragma unroll
      for(int j=0;j<4;j++){ float p_ = expf(s[i][j]-mn); pkeep[i][j] = p_; ps += p_; }
      for(int msk=1;msk<16;msk<<=1) ps += __shfl_xor(ps, msk, 64);
      l[i] = l[i]*sc + ps; m[i] = mn;
      #pragma unroll
      for(int j=0;j<4;j++) acc[i][j] *= sc;
    }
    __syncthreads();
    #pragma unroll
    for(int i=0;i<4;i++)
      #pragma unroll
      for(int j=0;j<4;j++) Ps[ty*4+i][tx*4+j] = pkeep[i][j];
    __syncthreads();
    for(int jj=0;jj<64;jj++){
      float pv[4], vv[4];
      #pragma unroll
      for(int i=0;i<4;i++) pv[i] = Ps[ty*4+i][jj];
      #pragma unroll
      for(int j=0;j<4;j++) vv[j] = Vs[jj][tx*4+j];
      #pragma unroll
      for(int i=0;i<4;i++)
        #pragma unroll
        for(int j=0;j<4;j++) acc[i][j] += pv[i]*vv[j];
    }
  }
  // Out layout: [t][h*64+d] (same as qlin) so gemm_resid consumes it directly
  #pragma unroll
  for(int i=0;i<4;i++){
    int qr = qt_*64 + ty*4 + i;
    float inv = (l[i] > 0.f) ? 1.f/l[i] : 0.f;
    #pragma unroll
    for(int j=0;j<4;j++)
      Out[((size_t)(b*S_+qr))*D_ + h*HD_ + tx*4+j] = acc[i][j]*inv;
  }
}

// ---------------- Router: one wave per token, f32 x ----------------
template<typename TW>
__global__ __launch_bounds__(64) void k_router(const float* __restrict__ X, const TW* __restrict__ W,
                                               float* __restrict__ probs, float* __restrict__ p01,
                                               int* __restrict__ idx0buf, int* __restrict__ list,
                                               int* __restrict__ cnt, const int* __restrict__ flag, int want){
  if(flag[0] != want) return;
  int t = blockIdx.x; int lane = threadIdx.x;
  float pe[8] = {};
  for(int d = lane; d < D_; d += 64){
    float xv = X[(size_t)t*D_ + d];
    const TW* wr = W + (size_t)d*E_;
    #pragma unroll
    for(int e=0;e<8;e++) pe[e] += xv*ldf(wr[e]);
  }
  for(int msk=1;msk<64;msk<<=1)
    #pragma unroll
    for(int e=0;e<8;e++) pe[e] += __shfl_xor(pe[e], msk, 64);
  if(lane == 0){
    float mx = pe[0];
    #pragma unroll
    for(int e=1;e<8;e++) mx = fmaxf(mx, pe[e]);
    float pr[8], sum = 0.f;
    #pragma unroll
    for(int e=0;e<8;e++){ pr[e] = expf(pe[e]-mx); sum += pr[e]; }
    #pragma unroll
    for(int e=0;e<8;e++){ pr[e] /= sum; probs[t*8+e] = pr[e]; }
    int i0 = 0;
    #pragma unroll
    for(int e=1;e<8;e++) if(pe[e] > pe[i0]) i0 = e;
    int i1 = -1;
    #pragma unroll
    for(int e=0;e<8;e++){ if(e==i0) continue; if(i1<0 || pe[e] > pe[i1]) i1 = e; }
    p01[t*2]   = pr[i0];
    p01[t*2+1] = pr[i1];
    idx0buf[t] = i0;
    int pos = atomicAdd(&cnt[i0], 1);
    if(pos >= 0 && pos < NT_) list[i0*NT_ + pos] = t*2;
    pos     = atomicAdd(&cnt[i1], 1);
    if(pos >= 0 && pos < NT_) list[i1*NT_ + pos] = t*2 + 1;
  }
}

__global__ __launch_bounds__(256) void k_stats(const float* __restrict__ probs, const int* __restrict__ idx0buf,
                                               float* __restrict__ cnt0f, float* __restrict__ psum){
  int e = blockIdx.x; int tid = threadIdx.x;
  float sp = 0.f, sc = 0.f;
  for(int n = tid; n < NT_; n += 256){ sp += probs[n*8+e]; sc += (idx0buf[n]==e) ? 1.f : 0.f; }
  __shared__ float r1[256], r2[256];
  r1[tid] = sp; r2[tid] = sc; __syncthreads();
  for(int st=128; st>0; st>>=1){ if(tid<st){ r1[tid]+=r1[tid+st]; r2[tid]+=r2[tid+st]; } __syncthreads(); }
  if(tid==0){ psum[e] = r1[0]; cnt0f[e] = r2[0]; }
}

__global__ void k_finish(const float* __restrict__ cnt0f, const float* __restrict__ psum,
                         const int* __restrict__ cnt, int* __restrict__ offs,
                         bf16* __restrict__ auxb, float* __restrict__ auxf, const int* __restrict__ flag){
  if(threadIdx.x==0 && blockIdx.x==0){
    int o = 0;
    for(int e=0;e<8;e++){ offs[e] = o; int c = cnt[e]; if(c < 0) c = 0; if(c > NT_) c = NT_; o += c; }
    float aux = 0.f;
    for(int e=0;e<8;e++) aux += (cnt0f[e]*(1.f/(float)NT_))*(psum[e]*(1.f/(float)NT_));
    float v = aux*0.01f*8.f;
    if(flag[0]) auxb[0] = f2b(v); else auxf[0] = v;
  }
}

// ---------------- Expert FFN stage1: silu(x@w1)*(x@w3), gathered rows, f32 x ----------------
template<typename TW>
__global__ __launch_bounds__(256) void k_ffn1(const float* __restrict__ X, const TW* __restrict__ W1,
                                              const TW* __restrict__ W3, bf16* __restrict__ Hout,
                                              const int* __restrict__ list, const int* __restrict__ cnt,
                                              const int* __restrict__ offs, int Mdense,
                                              const int* __restrict__ flag, int want){
  if(flag[0] != want) return;
  int e = blockIdx.z;
  int M = cnt ? cnt[e] : Mdense;
  if(M < 0) M = 0; if(M > NT_) M = NT_;
  int rt = blockIdx.y; if(rt*64 >= M) return;
  int jt = blockIdx.x;
  const TW* w1 = W1 + (size_t)e*D_*HIDDEN_;
  const TW* w3 = W3 + (size_t)e*D_*HIDDEN_;
  int outbase = offs ? offs[e] : 0;
  __shared__ float As[64][17];
  __shared__ float B1s[16][65];
  __shared__ float B3s[16][65];
  __shared__ int rowtok[64];
  int tid = threadIdx.x, tx = tid&15, ty = tid>>4;
  if(tid < 64){ int r = rt*64 + tid;
    rowtok[tid] = (r < M) ? (list ? (list[e*NT_ + r] >> 1) : r) : -1; }
  float a1[4][4] = {}, a3[4][4] = {};
  for(int k0=0;k0<D_;k0+=16){
    __syncthreads();
    #pragma unroll
    for(int p=0;p<4;p++){ int idx = tid + p*256; int r = idx>>4, c = idx&15;
      int tok = rowtok[r];
      As[r][c] = (tok>=0 && tok<NT_) ? X[(size_t)tok*D_ + k0 + c] : 0.f; }
    #pragma unroll
    for(int p=0;p<4;p++){ int idx = tid + p*256; int r = idx>>6, c = idx&63;
      int gn = jt*64 + c; float v1 = 0.f, v3 = 0.f;
      if(gn < HIDDEN_){ size_t o = (size_t)(k0+r)*HIDDEN_ + gn; v1 = ldf(w1[o]); v3 = ldf(w3[o]); }
      B1s[r][c] = v1; B3s[r][c] = v3; }
    __syncthreads();
    #pragma unroll
    for(int kk=0;kk<16;kk++){
      float a[4], b1[4], b3[4];
      #pragma unroll
      for(int i=0;i<4;i++) a[i] = As[ty*4+i][kk];
      #pragma unroll
      for(int j=0;j<4;j++){ b1[j] = B1s[kk][tx*4+j]; b3[j] = B3s[kk][tx*4+j]; }
      #pragma unroll
      for(int i=0;i<4;i++)
        #pragma unroll
        for(int j=0;j<4;j++){ a1[i][j] += a[i]*b1[j]; a3[i][j] += a[i]*b3[j]; }
    }
  }
  #pragma unroll
  for(int i=0;i<4;i++){ int r = rt*64 + ty*4 + i; if(r >= M) continue;
    #pragma unroll
    for(int j=0;j<4;j++){ int gn = jt*64 + tx*4 + j; if(gn >= HIDDEN_) continue;
      float sg = a1[i][j];
      float val = (sg/(1.f+expf(-sg)))*a3[i][j];
      Hout[(size_t)(outbase+r)*HIDDEN_ + gn] = f2b(val); } }
}

// ---------------- Expert FFN stage2: h @ w2 -> scatter bf16 EO[(token,slot)] ----------------
template<typename TW>
__global__ __launch_bounds__(256) void k_ffn2(const bf16* __restrict__ Hin, const TW* __restrict__ W2,
                                              bf16* __restrict__ EO, const int* __restrict__ list,
                                              const int* __restrict__ cnt, const int* __restrict__ offs,
                                              const int* __restrict__ flag, int want){
  if(flag[0] != want) return;
  int e = blockIdx.z;
  int M = cnt[e];
  if(M < 0) M = 0; if(M > NT_) M = NT_;
  int rt = blockIdx.y; if(rt*64 >= M) return;
  int nt = blockIdx.x;
  const TW* w2 = W2 + (size_t)e*HIDDEN_*D_;
  int base = offs[e];
  __shared__ float As[64][17];
  __shared__ float Bs[16][65];
  int tid = threadIdx.x, tx = tid&15, ty = tid>>4;
  float acc[4][4] = {};
  for(int k0=0;k0<HIDDEN_;k0+=16){
    __syncthreads();
    #pragma unroll
    for(int p=0;p<4;p++){ int idx = tid + p*256; int r = idx>>4, c = idx&15;
      int row = rt*64 + r; int gk = k0 + c;
      As[r][c] = (row<M && gk<HIDDEN_) ? b2f(Hin[(size_t)(base+row)*HIDDEN_ + gk]) : 0.f; }
    #pragma unroll
    for(int p=0;p<4;p++){ int idx = tid + p*256; int r = idx>>6, c = idx&63;
      int gk = k0 + r;
      Bs[r][c] = (gk<HIDDEN_) ? ldf(w2[(size_t)gk*D_ + nt*64 + c]) : 0.f; }
    __syncthreads();
    #pragma unroll
    for(int kk=0;kk<16;kk++){
      float a[4], b[4];
      #pragma unroll
      for(int i=0;i<4;i++) a[i] = As[ty*4+i][kk];
      #pragma unroll
      for(int j=0;j<4;j++) b[j] = Bs[kk][tx*4+j];
      #pragma unroll
      for(int i=0;i<4;i++)
        #pragma unroll
        for(int j=0;j<4;j++) acc[i][j] += a[i]*b[j];
    }
  }
  #pragma unroll
  for(int i=0;i<4;i++){ int row = rt*64 + ty*4 + i; if(row >= M) continue;
    int dst = list[e*NT_ + row];
    if(dst < 0 || dst >= 2*NT_) continue;
    #pragma unroll
    for(int j=0;j<4;j++)
      EO[(size_t)dst*D_ + nt*64 + tx*4 + j] = f2b(acc[i][j]); }
}

// Shared-expert stage2: dense rows, accumulate f32 into dst (hbuf) — one RMW per element
template<typename TW>
__global__ __launch_bounds__(256) void k_ffn2_acc(const bf16* __restrict__ Hin, const TW* __restrict__ W2,
                                                  float* __restrict__ dst,
                                                  const int* __restrict__ flag, int want){
  if(flag[0] != want) return;
  int rt = blockIdx.y;
  int nt = blockIdx.x;
  __shared__ float As[64][17];
  __shared__ float Bs[16][65];
  int tid = threadIdx.x, tx = tid&15, ty = tid>>4;
  float acc[4][4] = {};
  for(int k0=0;k0<HIDDEN_;k0+=16){
    __syncthreads();
    #pragma unroll
    for(int p=0;p<4;p++){ int idx = tid + p*256; int r = idx>>4, c = idx&15;
      int row = rt*64 + r; int gk = k0 + c;
      As[r][c] = (gk<HIDDEN_) ? b2f(Hin[(size_t)row*HIDDEN_ + gk]) : 0.f; }
    #pragma unroll
    for(int p=0;p<4;p++){ int idx = tid + p*256; int r = idx>>6, c = idx&63;
      int gk = k0 + r;
      Bs[r][c] = (gk<HIDDEN_) ? ldf(W2[(size_t)gk*D_ + nt*64 + c]) : 0.f; }
    __syncthreads();
    #pragma unroll
    for(int kk=0;kk<16;kk++){
      float a[4], b[4];
      #pragma unroll
      for(int i=0;i<4;i++) a[i] = As[ty*4+i][kk];
      #pragma unroll
      for(int j=0;j<4;j++) b[j] = Bs[kk][tx*4+j];
      #pragma unroll
      for(int i=0;i<4;i++)
        #pragma unroll
        for(int j=0;j<4;j++) acc[i][j] += a[i]*b[j];
    }
  }
  #pragma unroll
  for(int i=0;i<4;i++){ int row = rt*64 + ty*4 + i;
    #pragma unroll
    for(int j=0;j<4;j++){
      size_t o = (size_t)row*D_ + nt*64 + tx*4 + j;
      dst[o] = dst[o] + acc[i][j]; } }
}

// ---------------- Combine: out = h(+shared) + p0*eo0 + p1*eo1 ----------------
__global__ __launch_bounds__(256) void k_combine(const float* __restrict__ hbuf, const bf16* __restrict__ eosl,
                                                 const float* __restrict__ p01,
                                                 bf16* __restrict__ outb, float* __restrict__ outf,
                                                 const int* __restrict__ flag){
  int t = blockIdx.x; int tid = threadIdx.x;
  int isbf = flag[0];
  float p0 = p01[t*2], p1 = p01[t*2+1];
  #pragma unroll
  for(int i=0;i<4;i++){
    int d = tid + i*256;
    float v = hbuf[(size_t)t*D_ + d]
            + p0*b2f(eosl[((size_t)(t*2))*D_ + d])
            + p1*b2f(eosl[((size_t)(t*2+1))*D_ + d]);
    size_t o = (size_t)t*D_ + d;
    if(isbf) outb[o] = f2b(v); else outf[o] = v;
  }
}

// ---------------- workspace layout (bytes), total 67,453,060 ----------------
// Phase A:
static const size_t O_XN   = 0;          // f32 4096x1024  [0, 16777216)
static const size_t O_QLIN = 16777216;   // f32 4096x1024  [.., 33554432)  (rope in-place; read by attn)
static const size_t O_KLIN = 33554432;   // f32 4096x256   [.., 37748736)
static const size_t O_VLIN = 37748736;   // f32 4096x256   [.., 41943040)
static const size_t O_AOUT = 41943040;   // f32 4096x1024  [.., 58720256)
static const size_t O_HBUF = 0;          // f32 4096x1024 (over XN; XN dead after QKV GEMMs)
// Phase B overlays (all Phase-A tensors except HBUF dead):
static const size_t O_XN2  = 16777216;   // f32 4096x1024 (over QLIN)      ends 33554432
static const size_t O_HEXP = 33554432;   // bf16 8192x684 (over KLIN/VLIN) ends 44761088
static const size_t O_SHH  = 44761088;   // bf16 4096x684 (over AOUT head) ends 50364416
static const size_t O_EOSL = 50364416;   // bf16 8192x1024 (over AOUT)     ends 67141632
static const size_t O_PROBS= 67141632;   // f32 4096x8   ends 67272704
static const size_t O_P01  = 67272704;   // f32 4096x2   ends 67305472
static const size_t O_IDX0 = 67305472;   // int 4096     ends 67321856
static const size_t O_LIST = 67321856;   // int 8x4096   ends 67452928
static const size_t O_CNT  = 67452928;   // int 8
static const size_t O_CNT0 = 67452960;   // f32 8
static const size_t O_PSUM = 67452992;   // f32 8
static const size_t O_OFFS = 67453024;   // int 8
static const size_t O_FLAG = 67453056;   // int 1        ends 67453060

extern "C" void kernel_launch(void* const* d_in, const int* in_sizes, int n_in,
                              void* d_out, int out_size, void* d_ws, size_t ws_size,
                              hipStream_t stream){
  (void)in_sizes; (void)n_in; (void)out_size; (void)ws_size;
  char* ws = (char*)d_ws;
  float* xn   = (float*)(ws + O_XN);
  float* qlin = (float*)(ws + O_QLIN);
  float* klin = (float*)(ws + O_KLIN);
  float* vlin = (float*)(ws + O_VLIN);
  float* aout = (float*)(ws + O_AOUT);
  float* hbuf = (float*)(ws + O_HBUF);
  float* xn2  = (float*)(ws + O_XN2);
  bf16* hexp  = (bf16*)(ws + O_HEXP);
  bf16* shh   = (bf16*)(ws + O_SHH);
  bf16* eosl  = (bf16*)(ws + O_EOSL);
  float* probs=(float*)(ws + O_PROBS);
  float* p01 = (float*)(ws + O_P01);
  int*  idx0 = (int*)(ws + O_IDX0);
  int*  list = (int*)(ws + O_LIST);
  int*  cnt  = (int*)(ws + O_CNT);
  float* cnt0f=(float*)(ws + O_CNT0);
  float* psum= (float*)(ws + O_PSUM);
  int*  offs = (int*)(ws + O_OFFS);
  int*  flg  = (int*)(ws + O_FLAG);

  bf16* outb = (bf16*)d_out;
  float* outf = (float*)d_out;
  bf16* auxb = outb + (size_t)NT_*D_;
  float* auxf = outf + (size_t)NT_*D_;

  k_detect<<<1, 64, 0, stream>>>((const uint32_t*)d_in[14], flg, cnt);

  // ---- attention block ----
  k_rms<bf16,bf16>  <<<NT_, 256, 0, stream>>>((const bf16*)d_in[0], (const bf16*)d_in[14], xn, flg, 1);
  k_rms<float,float><<<NT_, 256, 0, stream>>>((const float*)d_in[0], (const float*)d_in[14], xn, flg, 0);

  k_gemm<bf16> <<<dim3(16,64), 256, 0, stream>>>(xn, (const bf16*)d_in[3], qlin, NT_, D_, D_, flg, 1);
  k_gemm<float><<<dim3(16,64), 256, 0, stream>>>(xn, (const float*)d_in[3], qlin, NT_, D_, D_, flg, 0);
  k_gemm<bf16> <<<dim3(4,64), 256, 0, stream>>>(xn, (const bf16*)d_in[4], klin, NT_, HKV_*HD_, D_, flg, 1);
  k_gemm<float><<<dim3(4,64), 256, 0, stream>>>(xn, (const float*)d_in[4], klin, NT_, HKV_*HD_, D_, flg, 0);
  k_gemm<bf16> <<<dim3(4,64), 256, 0, stream>>>(xn, (const bf16*)d_in[5], vlin, NT_, HKV_*HD_, D_, flg, 1);
  k_gemm<float><<<dim3(4,64), 256, 0, stream>>>(xn, (const float*)d_in[5], vlin, NT_, HKV_*HD_, D_, flg, 0);

  k_rope<bf16> <<<NT_, 256, 0, stream>>>(qlin, klin, (const bf16*)d_in[1], (const bf16*)d_in[2], flg, 1);
  k_rope<float><<<NT_, 256, 0, stream>>>(qlin, klin, (const float*)d_in[1], (const float*)d_in[2], flg, 0);

  k_attn<<<dim3(S_/64, H_, B_), 256, 0, stream>>>(qlin, klin, vlin, aout);

  k_gemm_resid<bf16> <<<dim3(16,64), 256, 0, stream>>>(aout, (const bf16*)d_in[6], (const bf16*)d_in[0], hbuf, NT_, D_, D_, flg, 1);
  k_gemm_resid<float><<<dim3(16,64), 256, 0, stream>>>(aout, (const float*)d_in[6], (const float*)d_in[0], hbuf, NT_, D_, D_, flg, 0);

  // ---- MoE block ----
  k_rms<float,bf16> <<<NT_, 256, 0, stream>>>(hbuf, (const bf16*)d_in[15], xn2, flg, 1);
  k_rms<float,float><<<NT_, 256, 0, stream>>>(hbuf, (const float*)d_in[15], xn2, flg, 0);

  k_router<bf16> <<<NT_, 64, 0, stream>>>(xn2, (const bf16*)d_in[7], probs, p01, idx0, list, cnt, flg, 1);
  k_router<float><<<NT_, 64, 0, stream>>>(xn2, (const float*)d_in[7], probs, p01, idx0, list, cnt, flg, 0);

  k_stats<<<E_, 256, 0, stream>>>(probs, idx0, cnt0f, psum);
  k_finish<<<1, 64, 0, stream>>>(cnt0f, psum, cnt, offs, auxb, auxf, flg);

  k_ffn1<bf16> <<<dim3(11, 64, E_), 256, 0, stream>>>(xn2, (const bf16*)d_in[8], (const bf16*)d_in[10], hexp, list, cnt, offs, 0, flg, 1);
  k_ffn1<float><<<dim3(11, 64, E_), 256, 0, stream>>>(xn2, (const float*)d_in[8], (const float*)d_in[10], hexp, list, cnt, offs, 0, flg, 0);
  k_ffn1<bf16> <<<dim3(11, 64, 1), 256, 0, stream>>>(xn2, (const bf16*)d_in[11], (const bf16*)d_in[13], shh, nullptr, nullptr, nullptr, NT_, flg, 1);
  k_ffn1<float><<<dim3(11, 64, 1), 256, 0, stream>>>(xn2, (const float*)d_in[11], (const float*)d_in[13], shh, nullptr, nullptr, nullptr, NT_, flg, 0);

  k_ffn2<bf16> <<<dim3(16, 64, E_), 256, 0, stream>>>(hexp, (const bf16*)d_in[9], eosl, list, cnt, offs, flg, 1);
  k_ffn2<float><<<dim3(16, 64, E_), 256, 0, stream>>>(hexp, (const float*)d_in[9], eosl, list, cnt, offs, flg, 0);

  k_ffn2_acc<bf16> <<<dim3(16, 64), 256, 0, stream>>>(shh, (const bf16*)d_in[12], hbuf, flg, 1);
  k_ffn2_acc<float><<<dim3(16, 64), 256, 0, stream>>>(shh, (const float*)d_in[12], hbuf, flg, 0);

  k_combine<<<NT_, 256, 0, stream>>>(hbuf, eosl, p01, outb, outf, flg);
}

// Round 6
// 2889.568 us; speedup vs baseline: 1.1422x; 1.1422x over previous
//
#include <hip/hip_runtime.h>
#include <hip/hip_bf16.h>
#include <cstdint>

#define B_ 2
#define S_ 2048
#define D_ 1024
#define H_ 16
#define HKV_ 4
#define HD_ 64
#define E_ 8
#define HIDDEN_ 684
#define NT_ (B_*S_)   // 4096 tokens
#define NEGBIG (-1e30f)

using bf16 = __hip_bfloat16;
typedef __attribute__((ext_vector_type(8))) short short8v;
typedef __attribute__((ext_vector_type(4))) float f32x4;

static __device__ __forceinline__ float b2f(bf16 v){ return __bfloat162float(v); }
static __device__ __forceinline__ bf16 f2b(float v){ return __float2bfloat16(v); }
static __device__ __forceinline__ float ldf(float v){ return v; }
static __device__ __forceinline__ float ldf(bf16 v){ return __bfloat162float(v); }
static __device__ __forceinline__ short f2bs(float v){ bf16 h = f2b(v); return *reinterpret_cast<short*>(&h); }

// Detect device float dtype from g_attn == ones(1024). flag=1 => bf16.
__global__ void k_detect(const uint32_t* __restrict__ g, int* __restrict__ flag, int* __restrict__ cnt){
  if(threadIdx.x == 0 && blockIdx.x == 0){
    uint32_t w0 = g[0], w1 = g[1], w2 = g[2], w3 = g[3];
    int bf;
    if(w0==0x3F803F80u && w1==0x3F803F80u && w2==0x3F803F80u && w3==0x3F803F80u) bf = 1;
    else if(w0==0x3F800000u && w1==0x3F800000u && w2==0x3F800000u && w3==0x3F800000u) bf = 0;
    else bf = 1;
    flag[0] = bf;
  }
  if(threadIdx.x < E_ && blockIdx.x == 0) cnt[threadIdx.x] = 0;
}

// ---------------- RMSNorm -> f32 out ----------------
template<typename TX, typename TG>
__global__ __launch_bounds__(256) void k_rms(const TX* __restrict__ X, const TG* __restrict__ g,
                                             float* __restrict__ out, const int* __restrict__ flag, int want){
  if(flag[0] != want) return;
  int t = blockIdx.x; int tid = threadIdx.x;
  const TX* xr = X + (size_t)t*D_;
  float v[4]; float ss = 0.f;
  #pragma unroll
  for(int i=0;i<4;i++){ v[i] = ldf(xr[tid + i*256]); ss += v[i]*v[i]; }
  __shared__ float red[256];
  red[tid] = ss; __syncthreads();
  for(int st=128; st>0; st>>=1){ if(tid<st) red[tid] += red[tid+st]; __syncthreads(); }
  float r = rsqrtf(red[0]*(1.f/(float)D_) + 1e-5f);
  #pragma unroll
  for(int i=0;i<4;i++){
    int d = tid + i*256;
    out[(size_t)t*D_ + d] = v[i]*r*ldf(g[d]);
  }
}

// =====================================================================
// Unified MFMA GEMM: C = A @ B  (A: M x K, dtype TA;  B: K x N, dtype TB)
// 128x128 tile, BK=32, 4 waves, mfma_f32_16x16x32_bf16, fp32 accum.
// AMAP: 0 dense row, 1 base+row (contig), 2 gather via list>>1
// OMODE: 0 f32 store, 1 f32 store + resid(TB), 2 bf16 scatter via list,
//        3 f32 accumulate (dense), 4 bf16 store (base+row)
// Expert mode iff cnt != nullptr: M=cnt[e], base=offs[e], B += e*K*N.
// =====================================================================
#define ASTRIDE 40   // shorts per LDS row (80B, 16B-aligned, 2-way banks)

static __device__ __forceinline__ f32x4 mfma16(short8v a, short8v b, f32x4 c){
  return __builtin_amdgcn_mfma_f32_16x16x32_bf16(a, b, c, 0, 0, 0);
}

template<typename TA, typename TB, int AMAP, int OMODE>
__global__ __launch_bounds__(256) void k_mgemm(
    const TA* __restrict__ A, const TB* __restrict__ Bw, void* __restrict__ Cout,
    const TB* __restrict__ resid,
    int M, int N, int K, int ldc,
    const int* __restrict__ cnt, const int* __restrict__ offs, const int* __restrict__ list,
    const int* __restrict__ flag, int want)
{
  if(flag[0] != want) return;
  int e = blockIdx.z;
  int base = 0;
  if(cnt){
    M = cnt[e]; if(M < 0) M = 0; if(M > NT_) M = NT_;
    base = offs[e];
    Bw += (size_t)e * (size_t)K * (size_t)N;
  }
  int m0 = blockIdx.y*128; if(m0 >= M) return;
  int n0 = blockIdx.x*128;

  __shared__ short As[128*ASTRIDE];
  __shared__ short Bs[128*ASTRIDE];   // [col][k]
  __shared__ int rowA[128];

  int tid = threadIdx.x;
  int w = tid>>6, l = tid&63;
  int wr = w>>1, wc = w&1;
  int lr = l&15, lg = l>>4;

  if(tid < 128){
    int rloc = m0 + tid;
    int ar = -1;
    if(rloc < M){
      if(AMAP==2) ar = list[e*NT_ + rloc] >> 1;
      else if(AMAP==1) ar = base + rloc;
      else ar = rloc;
    }
    rowA[tid] = ar;
  }

  f32x4 acc[4][4] = {};

  int KT = (K + 31) >> 5;
  int srow = tid>>1, skh = (tid&1)*16;       // A staging: row, k-half
  int bk = tid>>3, bnc = (tid&7)*16;         // B staging: k, col-seg
  for(int kt = 0; kt < KT; ++kt){
    int k0 = kt*32;
    __syncthreads();
    // ---- stage A tile (128 x 32) as bf16 ----
    {
      int ar = rowA[srow];
      short tmp[16];
      #pragma unroll
      for(int i=0;i<16;i++){
        int gk = k0 + skh + i;
        float v = 0.f;
        if(ar >= 0 && gk < K) v = ldf(A[(size_t)ar*K + gk]);
        tmp[i] = f2bs(v);
      }
      short8v* dst = (short8v*)&As[srow*ASTRIDE + skh];
      short8v v0, v1;
      #pragma unroll
      for(int i=0;i<8;i++){ v0[i] = tmp[i]; v1[i] = tmp[8+i]; }
      dst[0] = v0; dst[1] = v1;
    }
    // ---- stage B tile (32 x 128) transposed: Bs[col][k] ----
    {
      int gk = k0 + bk;
      #pragma unroll
      for(int i=0;i<16;i++){
        int gn = n0 + bnc + i;
        float v = 0.f;
        if(gk < K && gn < N) v = ldf(Bw[(size_t)gk*N + gn]);
        Bs[(bnc+i)*ASTRIDE + bk] = f2bs(v);
      }
    }
    __syncthreads();
    // ---- fragments + MFMA ----
    short8v a[4], b[4];
    #pragma unroll
    for(int f=0; f<4; f++){
      a[f] = *(const short8v*)&As[(wr*64 + f*16 + lr)*ASTRIDE + lg*8];
      b[f] = *(const short8v*)&Bs[(wc*64 + f*16 + lr)*ASTRIDE + lg*8];
    }
    #pragma unroll
    for(int fi=0;fi<4;fi++)
      #pragma unroll
      for(int fj=0;fj<4;fj++)
        acc[fi][fj] = mfma16(a[fi], b[fj], acc[fi][fj]);
  }

  // ---- store: frag (fi,fj), lane l -> row = lg*4+r, col = lr ----
  #pragma unroll
  for(int fi=0;fi<4;fi++){
    #pragma unroll
    for(int r=0;r<4;r++){
      int rl = m0 + wr*64 + fi*16 + lg*4 + r;
      if(rl >= M) continue;
      int orow;
      if(OMODE==2){ orow = list[e*NT_ + rl]; if(orow < 0 || orow >= 2*NT_) continue; }
      else orow = base + rl;
      #pragma unroll
      for(int fj=0;fj<4;fj++){
        int gcol = n0 + wc*64 + fj*16 + lr;
        if(gcol >= N) continue;
        float v = acc[fi][fj][r];
        size_t o = (size_t)orow*ldc + gcol;
        if(OMODE==0)      ((float*)Cout)[o] = v;
        else if(OMODE==1) ((float*)Cout)[o] = v + ldf(resid[o]);
        else if(OMODE==2) ((bf16*)Cout)[o] = f2b(v);
        else if(OMODE==3) ((float*)Cout)[o] = ((float*)Cout)[o] + v;
        else              ((bf16*)Cout)[o] = f2b(v);
      }
    }
  }
}

// ---------------- silu(t1)*t3 elementwise, bf16 ----------------
__global__ __launch_bounds__(256) void k_silu(const bf16* __restrict__ t1, const bf16* __restrict__ t3,
                                              bf16* __restrict__ out, int n4){
  int i = blockIdx.x*256 + threadIdx.x;
  if(i >= n4) return;
  #pragma unroll
  for(int j=0;j<4;j++){
    int idx = i*4 + j;
    float a = b2f(t1[idx]);
    out[idx] = f2b((a/(1.f+expf(-a))) * b2f(t3[idx]));
  }
}

// ---------------- RoPE in-place on q (4096x1024) and k (4096x256), f32 ----------------
template<typename TF>
__global__ __launch_bounds__(256) void k_rope(float* __restrict__ ql, float* __restrict__ kl,
                                              const TF* __restrict__ fc, const TF* __restrict__ fs,
                                              const int* __restrict__ flag, int want){
  if(flag[0] != want) return;
  int t = blockIdx.x; int s = t % S_;
  int tid = threadIdx.x;
  for(int p0 = tid; p0 < 512; p0 += 256){
    int h = p0>>5, p = p0&31;
    float c = ldf(fc[s*32+p]), sn = ldf(fs[s*32+p]);
    size_t o = (size_t)t*D_ + h*64 + 2*p;
    float xr = ql[o], xi = ql[o+1];
    ql[o]   = xr*c - xi*sn;
    ql[o+1] = xr*sn + xi*c;
  }
  if(tid < 128){
    int h = tid>>5, p = tid&31;
    float c = ldf(fc[s*32+p]), sn = ldf(fs[s*32+p]);
    size_t o = (size_t)t*256 + h*64 + 2*p;
    float xr = kl[o], xi = kl[o+1];
    kl[o]   = xr*c - xi*sn;
    kl[o+1] = xr*sn + xi*c;
  }
}

// ---------------- Flash attention, f32, strided [t, h*64+d] layout ----------------
__global__ __launch_bounds__(256) void k_attn(const float* __restrict__ Q, const float* __restrict__ Kg,
                                              const float* __restrict__ V, float* __restrict__ Out){
  int qt_ = (S_/64 - 1) - blockIdx.x;
  int h = blockIdx.y, b = blockIdx.z;
  int kvh = h>>2;
  const float* qb = Q + (size_t)b*S_*D_ + (size_t)h*HD_;
  const float* kb = Kg + (size_t)b*S_*(HKV_*HD_) + (size_t)kvh*HD_;
  const float* vb = V  + (size_t)b*S_*(HKV_*HD_) + (size_t)kvh*HD_;
  __shared__ float Qs[64][65];
  __shared__ float Ks[64][65];
  __shared__ float Vs[64][65];
  float (*Ps)[65] = Ks;
  int tid = threadIdx.x, tx = tid&15, ty = tid>>4;
  #pragma unroll
  for(int p=0;p<16;p++){ int idx = tid + p*256; int r = idx>>6, d = idx&63;
    Qs[r][d] = qb[(size_t)(qt_*64+r)*D_ + d] * 0.125f; }
  float m[4], l[4], acc[4][4] = {};
  #pragma unroll
  for(int i=0;i<4;i++){ m[i] = NEGBIG; l[i] = 0.f; }
  for(int kt=0; kt<=qt_; kt++){
    __syncthreads();
    #pragma unroll
    for(int p=0;p<16;p++){ int idx = tid + p*256; int r = idx>>6, d = idx&63;
      Ks[r][d] = kb[(size_t)(kt*64+r)*256 + d];
      Vs[r][d] = vb[(size_t)(kt*64+r)*256 + d]; }
    __syncthreads();
    float s[4][4] = {};
    for(int d=0; d<64; d++){
      float a[4], bb[4];
      #pragma unroll
      for(int i=0;i<4;i++) a[i] = Qs[ty*4+i][d];
      #pragma unroll
      for(int j=0;j<4;j++) bb[j] = Ks[tx*4+j][d];
      #pragma unroll
      for(int i=0;i<4;i++)
        #pragma unroll
        for(int j=0;j<4;j++) s[i][j] += a[i]*bb[j];
    }
    if(kt == qt_){
      #pragma unroll
      for(int i=0;i<4;i++)
        #pragma unroll
        for(int j=0;j<4;j++) if(tx*4+j > ty*4+i) s[i][j] = NEGBIG;
    }
    float pkeep[4][4];
    #pragma unroll
    for(int i=0;i<4;i++){
      float mx = fmaxf(fmaxf(s[i][0],s[i][1]), fmaxf(s[i][2],s[i][3]));
      for(int msk=1;msk<16;msk<<=1) mx = fmaxf(mx, __shfl_xor(mx, msk, 64));
      float mn = fmaxf(m[i], mx);
      float sc = expf(m[i]-mn);
      float ps = 0.f;
      #pragma unroll
      for(int j=0;j<4;j++){ float p_ = expf(s[i][j]-mn); pkeep[i][j] = p_; ps += p_; }
      for(int msk=1;msk<16;msk<<=1) ps += __shfl_xor(ps, msk, 64);
      l[i] = l[i]*sc + ps; m[i] = mn;
      #pragma unroll
      for(int j=0;j<4;j++) acc[i][j] *= sc;
    }
    __syncthreads();
    #pragma unroll
    for(int i=0;i<4;i++)
      #pragma unroll
      for(int j=0;j<4;j++) Ps[ty*4+i][tx*4+j] = pkeep[i][j];
    __syncthreads();
    for(int jj=0;jj<64;jj++){
      float pv[4], vv[4];
      #pragma unroll
      for(int i=0;i<4;i++) pv[i] = Ps[ty*4+i][jj];
      #pragma unroll
      for(int j=0;j<4;j++) vv[j] = Vs[jj][tx*4+j];
      #pragma unroll
      for(int i=0;i<4;i++)
        #pragma unroll
        for(int j=0;j<4;j++) acc[i][j] += pv[i]*vv[j];
    }
  }
  #pragma unroll
  for(int i=0;i<4;i++){
    int qr = qt_*64 + ty*4 + i;
    float inv = (l[i] > 0.f) ? 1.f/l[i] : 0.f;
    #pragma unroll
    for(int j=0;j<4;j++)
      Out[((size_t)(b*S_+qr))*D_ + h*HD_ + tx*4+j] = acc[i][j]*inv;
  }
}

// ---------------- Router: one wave per token, f32 x ----------------
template<typename TW>
__global__ __launch_bounds__(64) void k_router(const float* __restrict__ X, const TW* __restrict__ W,
                                               float* __restrict__ probs, float* __restrict__ p01,
                                               int* __restrict__ idx0buf, int* __restrict__ list,
                                               int* __restrict__ cnt, const int* __restrict__ flag, int want){
  if(flag[0] != want) return;
  int t = blockIdx.x; int lane = threadIdx.x;
  float pe[8] = {};
  for(int d = lane; d < D_; d += 64){
    float xv = X[(size_t)t*D_ + d];
    const TW* wr = W + (size_t)d*E_;
    #pragma unroll
    for(int e=0;e<8;e++) pe[e] += xv*ldf(wr[e]);
  }
  for(int msk=1;msk<64;msk<<=1)
    #pragma unroll
    for(int e=0;e<8;e++) pe[e] += __shfl_xor(pe[e], msk, 64);
  if(lane == 0){
    float mx = pe[0];
    #pragma unroll
    for(int e=1;e<8;e++) mx = fmaxf(mx, pe[e]);
    float pr[8], sum = 0.f;
    #pragma unroll
    for(int e=0;e<8;e++){ pr[e] = expf(pe[e]-mx); sum += pr[e]; }
    #pragma unroll
    for(int e=0;e<8;e++){ pr[e] /= sum; probs[t*8+e] = pr[e]; }
    int i0 = 0;
    #pragma unroll
    for(int e=1;e<8;e++) if(pe[e] > pe[i0]) i0 = e;
    int i1 = -1;
    #pragma unroll
    for(int e=0;e<8;e++){ if(e==i0) continue; if(i1<0 || pe[e] > pe[i1]) i1 = e; }
    p01[t*2]   = pr[i0];
    p01[t*2+1] = pr[i1];
    idx0buf[t] = i0;
    int pos = atomicAdd(&cnt[i0], 1);
    if(pos >= 0 && pos < NT_) list[i0*NT_ + pos] = t*2;
    pos     = atomicAdd(&cnt[i1], 1);
    if(pos >= 0 && pos < NT_) list[i1*NT_ + pos] = t*2 + 1;
  }
}

__global__ __launch_bounds__(256) void k_stats(const float* __restrict__ probs, const int* __restrict__ idx0buf,
                                               float* __restrict__ cnt0f, float* __restrict__ psum){
  int e = blockIdx.x; int tid = threadIdx.x;
  float sp = 0.f, sc = 0.f;
  for(int n = tid; n < NT_; n += 256){ sp += probs[n*8+e]; sc += (idx0buf[n]==e) ? 1.f : 0.f; }
  __shared__ float r1[256], r2[256];
  r1[tid] = sp; r2[tid] = sc; __syncthreads();
  for(int st=128; st>0; st>>=1){ if(tid<st){ r1[tid]+=r1[tid+st]; r2[tid]+=r2[tid+st]; } __syncthreads(); }
  if(tid==0){ psum[e] = r1[0]; cnt0f[e] = r2[0]; }
}

__global__ void k_finish(const float* __restrict__ cnt0f, const float* __restrict__ psum,
                         const int* __restrict__ cnt, int* __restrict__ offs,
                         bf16* __restrict__ auxb, float* __restrict__ auxf, const int* __restrict__ flag){
  if(threadIdx.x==0 && blockIdx.x==0){
    int o = 0;
    for(int e=0;e<8;e++){ offs[e] = o; int c = cnt[e]; if(c < 0) c = 0; if(c > NT_) c = NT_; o += c; }
    float aux = 0.f;
    for(int e=0;e<8;e++) aux += (cnt0f[e]*(1.f/(float)NT_))*(psum[e]*(1.f/(float)NT_));
    float v = aux*0.01f*8.f;
    if(flag[0]) auxb[0] = f2b(v); else auxf[0] = v;
  }
}

// ---------------- Combine: out = h(+shared) + p0*eo0 + p1*eo1 ----------------
__global__ __launch_bounds__(256) void k_combine(const float* __restrict__ hbuf, const bf16* __restrict__ eosl,
                                                 const float* __restrict__ p01,
                                                 bf16* __restrict__ outb, float* __restrict__ outf,
                                                 const int* __restrict__ flag){
  int t = blockIdx.x; int tid = threadIdx.x;
  int isbf = flag[0];
  float p0 = p01[t*2], p1 = p01[t*2+1];
  #pragma unroll
  for(int i=0;i<4;i++){
    int d = tid + i*256;
    float v = hbuf[(size_t)t*D_ + d]
            + p0*b2f(eosl[((size_t)(t*2))*D_ + d])
            + p1*b2f(eosl[((size_t)(t*2+1))*D_ + d]);
    size_t o = (size_t)t*D_ + d;
    if(isbf) outb[o] = f2b(v); else outf[o] = v;
  }
}

// ---------------- workspace layout (bytes), peak ~67.5 MB ----------------
// Lifetime discipline: a region may be overlaid only after its LAST reader ran.
// Phase A:
static const size_t O_HBUF = 0;          // f32 4096x1024 [0, 16777216)  (xn shares this slot first)
static const size_t O_XN   = 0;          // f32 (dead after QKV gemms; hbuf overlays)
static const size_t O_QLIN = 16777216;   // f32 4096x1024 [.., 33554432)
static const size_t O_KLIN = 33554432;   // f32 4096x256  [.., 37748736)
static const size_t O_VLIN = 37748736;   // f32 4096x256  [.., 41943040)
static const size_t O_AOUT = 41943040;   // f32 4096x1024 [.., 58720256)
// Phase B (order: eff1 -> silu(expert) -> sff1 -> silu(shared) -> ffn2s):
static const size_t O_XN2  = 16777216;   // f32 4096x1024 (over QLIN)
static const size_t O_T1E  = 33554432;   // bf16 8192x684 -> 44761088
static const size_t O_T3E  = 44761088;   // bf16 8192x684 -> 55967744
static const size_t O_HEXP = 55967744;   // bf16 8192x684 -> 67174400
static const size_t O_T1S  = 33554432;   // bf16 4096x684 (over T1E — dead AFTER expert silu) -> 39157760
static const size_t O_T3S  = 39157760;   // bf16 4096x684 -> 44761088
static const size_t O_SHH  = 44761088;   // bf16 4096x684 (over T3E — dead after expert silu) -> 50364416
static const size_t O_EOSL = 16777216;   // bf16 8192x1024 (over XN2 — dead after ffn1s) -> 33554432
// control block:
static const size_t O_PROBS= 67174400;   // f32 4096x8  -> 67305472
static const size_t O_P01  = 67305472;   // f32 4096x2  -> 67338240
static const size_t O_IDX0 = 67338240;   // int 4096    -> 67354624
static const size_t O_LIST = 67354624;   // int 8x4096  -> 67485696
static const size_t O_CNT  = 67485696;
static const size_t O_CNT0 = 67485728;
static const size_t O_PSUM = 67485760;
static const size_t O_OFFS = 67485792;
static const size_t O_FLAG = 67485824;

extern "C" void kernel_launch(void* const* d_in, const int* in_sizes, int n_in,
                              void* d_out, int out_size, void* d_ws, size_t ws_size,
                              hipStream_t stream){
  (void)in_sizes; (void)n_in; (void)out_size; (void)ws_size;
  char* ws = (char*)d_ws;
  float* xn   = (float*)(ws + O_XN);
  float* qlin = (float*)(ws + O_QLIN);
  float* klin = (float*)(ws + O_KLIN);
  float* vlin = (float*)(ws + O_VLIN);
  float* aout = (float*)(ws + O_AOUT);
  float* hbuf = (float*)(ws + O_HBUF);
  float* xn2  = (float*)(ws + O_XN2);
  bf16* t1e   = (bf16*)(ws + O_T1E);
  bf16* t3e   = (bf16*)(ws + O_T3E);
  bf16* hexp  = (bf16*)(ws + O_HEXP);
  bf16* t1s   = (bf16*)(ws + O_T1S);
  bf16* t3s   = (bf16*)(ws + O_T3S);
  bf16* shh   = (bf16*)(ws + O_SHH);
  bf16* eosl  = (bf16*)(ws + O_EOSL);
  float* probs=(float*)(ws + O_PROBS);
  float* p01 = (float*)(ws + O_P01);
  int*  idx0 = (int*)(ws + O_IDX0);
  int*  list = (int*)(ws + O_LIST);
  int*  cnt  = (int*)(ws + O_CNT);
  float* cnt0f=(float*)(ws + O_CNT0);
  float* psum= (float*)(ws + O_PSUM);
  int*  offs = (int*)(ws + O_OFFS);
  int*  flg  = (int*)(ws + O_FLAG);

  bf16* outb = (bf16*)d_out;
  float* outf = (float*)d_out;
  bf16* auxb = outb + (size_t)NT_*D_;
  float* auxf = outf + (size_t)NT_*D_;

  k_detect<<<1, 64, 0, stream>>>((const uint32_t*)d_in[14], flg, cnt);

  // ---- attention block ----
  k_rms<bf16,bf16>  <<<NT_, 256, 0, stream>>>((const bf16*)d_in[0], (const bf16*)d_in[14], xn, flg, 1);
  k_rms<float,float><<<NT_, 256, 0, stream>>>((const float*)d_in[0], (const float*)d_in[14], xn, flg, 0);

  // QKV gemms (A=xn f32, M=4096, K=1024)
  k_mgemm<float,bf16,0,0> <<<dim3(8,32), 256, 0, stream>>>(xn, (const bf16*)d_in[3], qlin, nullptr, NT_, D_, D_, D_, nullptr, nullptr, nullptr, flg, 1);
  k_mgemm<float,float,0,0><<<dim3(8,32), 256, 0, stream>>>(xn, (const float*)d_in[3], qlin, nullptr, NT_, D_, D_, D_, nullptr, nullptr, nullptr, flg, 0);
  k_mgemm<float,bf16,0,0> <<<dim3(2,32), 256, 0, stream>>>(xn, (const bf16*)d_in[4], klin, nullptr, NT_, 256, D_, 256, nullptr, nullptr, nullptr, flg, 1);
  k_mgemm<float,float,0,0><<<dim3(2,32), 256, 0, stream>>>(xn, (const float*)d_in[4], klin, nullptr, NT_, 256, D_, 256, nullptr, nullptr, nullptr, flg, 0);
  k_mgemm<float,bf16,0,0> <<<dim3(2,32), 256, 0, stream>>>(xn, (const bf16*)d_in[5], vlin, nullptr, NT_, 256, D_, 256, nullptr, nullptr, nullptr, flg, 1);
  k_mgemm<float,float,0,0><<<dim3(2,32), 256, 0, stream>>>(xn, (const float*)d_in[5], vlin, nullptr, NT_, 256, D_, 256, nullptr, nullptr, nullptr, flg, 0);

  k_rope<bf16> <<<NT_, 256, 0, stream>>>(qlin, klin, (const bf16*)d_in[1], (const bf16*)d_in[2], flg, 1);
  k_rope<float><<<NT_, 256, 0, stream>>>(qlin, klin, (const float*)d_in[1], (const float*)d_in[2], flg, 0);

  k_attn<<<dim3(S_/64, H_, B_), 256, 0, stream>>>(qlin, klin, vlin, aout);

  // wo + residual -> hbuf (overlays xn, which is dead now)
  k_mgemm<float,bf16,0,1> <<<dim3(8,32), 256, 0, stream>>>(aout, (const bf16*)d_in[6], hbuf, (const bf16*)d_in[0], NT_, D_, D_, D_, nullptr, nullptr, nullptr, flg, 1);
  k_mgemm<float,float,0,1><<<dim3(8,32), 256, 0, stream>>>(aout, (const float*)d_in[6], hbuf, (const float*)d_in[0], NT_, D_, D_, D_, nullptr, nullptr, nullptr, flg, 0);

  // ---- MoE block ----
  k_rms<float,bf16> <<<NT_, 256, 0, stream>>>(hbuf, (const bf16*)d_in[15], xn2, flg, 1);
  k_rms<float,float><<<NT_, 256, 0, stream>>>(hbuf, (const float*)d_in[15], xn2, flg, 0);

  k_router<bf16> <<<NT_, 64, 0, stream>>>(xn2, (const bf16*)d_in[7], probs, p01, idx0, list, cnt, flg, 1);
  k_router<float><<<NT_, 64, 0, stream>>>(xn2, (const float*)d_in[7], probs, p01, idx0, list, cnt, flg, 0);

  k_stats<<<E_, 256, 0, stream>>>(probs, idx0, cnt0f, psum);
  k_finish<<<1, 64, 0, stream>>>(cnt0f, psum, cnt, offs, auxb, auxf, flg);

  // expert ffn1: t1e = gather(xn2) @ ew1, t3e = gather(xn2) @ ew3  (bf16 out)
  k_mgemm<float,bf16,2,4> <<<dim3(6,32,E_), 256, 0, stream>>>(xn2, (const bf16*)d_in[8], t1e, nullptr, 0, HIDDEN_, D_, HIDDEN_, cnt, offs, list, flg, 1);
  k_mgemm<float,float,2,4><<<dim3(6,32,E_), 256, 0, stream>>>(xn2, (const float*)d_in[8], t1e, nullptr, 0, HIDDEN_, D_, HIDDEN_, cnt, offs, list, flg, 0);
  k_mgemm<float,bf16,2,4> <<<dim3(6,32,E_), 256, 0, stream>>>(xn2, (const bf16*)d_in[10], t3e, nullptr, 0, HIDDEN_, D_, HIDDEN_, cnt, offs, list, flg, 1);
  k_mgemm<float,float,2,4><<<dim3(6,32,E_), 256, 0, stream>>>(xn2, (const float*)d_in[10], t3e, nullptr, 0, HIDDEN_, D_, HIDDEN_, cnt, offs, list, flg, 0);

  // expert silu FIRST: t1e/t3e become dead before shared ffn1 overlays them
  k_silu<<<(2*NT_*HIDDEN_/4 + 255)/256, 256, 0, stream>>>(t1e, t3e, hexp, 2*NT_*HIDDEN_/4);

  // shared ffn1 (dense, M=4096) — now legal to overlay t1e/t3e
  k_mgemm<float,bf16,0,4> <<<dim3(6,32), 256, 0, stream>>>(xn2, (const bf16*)d_in[11], t1s, nullptr, NT_, HIDDEN_, D_, HIDDEN_, nullptr, nullptr, nullptr, flg, 1);
  k_mgemm<float,float,0,4><<<dim3(6,32), 256, 0, stream>>>(xn2, (const float*)d_in[11], t1s, nullptr, NT_, HIDDEN_, D_, HIDDEN_, nullptr, nullptr, nullptr, flg, 0);
  k_mgemm<float,bf16,0,4> <<<dim3(6,32), 256, 0, stream>>>(xn2, (const bf16*)d_in[13], t3s, nullptr, NT_, HIDDEN_, D_, HIDDEN_, nullptr, nullptr, nullptr, flg, 1);
  k_mgemm<float,float,0,4><<<dim3(6,32), 256, 0, stream>>>(xn2, (const float*)d_in[13], t3s, nullptr, NT_, HIDDEN_, D_, HIDDEN_, nullptr, nullptr, nullptr, flg, 0);

  k_silu<<<(NT_*HIDDEN_/4 + 255)/256, 256, 0, stream>>>(t1s, t3s, shh, NT_*HIDDEN_/4);

  // expert ffn2: eosl[slot] = hexp[base+r] @ ew2  (scatter, bf16; overlays xn2 — dead now)
  k_mgemm<bf16,bf16,1,2> <<<dim3(8,32,E_), 256, 0, stream>>>(hexp, (const bf16*)d_in[9], eosl, nullptr, 0, D_, HIDDEN_, D_, cnt, offs, list, flg, 1);
  k_mgemm<bf16,float,1,2><<<dim3(8,32,E_), 256, 0, stream>>>(hexp, (const float*)d_in[9], eosl, nullptr, 0, D_, HIDDEN_, D_, cnt, offs, list, flg, 0);
  // shared ffn2: hbuf += shh @ sw2
  k_mgemm<bf16,bf16,0,3> <<<dim3(8,32), 256, 0, stream>>>(shh, (const bf16*)d_in[12], hbuf, nullptr, NT_, D_, HIDDEN_, D_, nullptr, nullptr, nullptr, flg, 1);
  k_mgemm<bf16,float,0,3><<<dim3(8,32), 256, 0, stream>>>(shh, (const float*)d_in[12], hbuf, nullptr, NT_, D_, HIDDEN_, D_, nullptr, nullptr, nullptr, flg, 0);

  k_combine<<<NT_, 256, 0, stream>>>(hbuf, eosl, p01, outb, outf, flg);
}

// Round 7
// 1200.707 us; speedup vs baseline: 2.7487x; 2.4066x over previous
//
#include <hip/hip_runtime.h>
#include <hip/hip_bf16.h>
#include <cstdint>

#define B_ 2
#define S_ 2048
#define D_ 1024
#define H_ 16
#define HKV_ 4
#define HD_ 64
#define E_ 8
#define HIDDEN_ 684
#define NT_ (B_*S_)   // 4096 tokens
#define NEGBIG (-1e30f)

using bf16 = __hip_bfloat16;
typedef __attribute__((ext_vector_type(8))) short short8v;
typedef __attribute__((ext_vector_type(4))) short short4v;
typedef __attribute__((ext_vector_type(4))) float f32x4;

static __device__ __forceinline__ float b2f(bf16 v){ return __bfloat162float(v); }
static __device__ __forceinline__ bf16 f2b(float v){ return __float2bfloat16(v); }
static __device__ __forceinline__ float ldf(float v){ return v; }
static __device__ __forceinline__ float ldf(bf16 v){ return __bfloat162float(v); }
static __device__ __forceinline__ short f2bs(float v){ bf16 h = f2b(v); return *reinterpret_cast<short*>(&h); }

// Detect device float dtype from g_attn == ones(1024). flag=1 => bf16.
__global__ void k_detect(const uint32_t* __restrict__ g, int* __restrict__ flag, int* __restrict__ cnt){
  if(threadIdx.x == 0 && blockIdx.x == 0){
    uint32_t w0 = g[0], w1 = g[1], w2 = g[2], w3 = g[3];
    int bf;
    if(w0==0x3F803F80u && w1==0x3F803F80u && w2==0x3F803F80u && w3==0x3F803F80u) bf = 1;
    else if(w0==0x3F800000u && w1==0x3F800000u && w2==0x3F800000u && w3==0x3F800000u) bf = 0;
    else bf = 1;
    flag[0] = bf;
  }
  if(threadIdx.x < E_ && blockIdx.x == 0) cnt[threadIdx.x] = 0;
}

// ---------------- RMSNorm -> f32 out ----------------
template<typename TX, typename TG>
__global__ __launch_bounds__(256) void k_rms(const TX* __restrict__ X, const TG* __restrict__ g,
                                             float* __restrict__ out, const int* __restrict__ flag, int want){
  if(flag[0] != want) return;
  int t = blockIdx.x; int tid = threadIdx.x;
  const TX* xr = X + (size_t)t*D_;
  float v[4]; float ss = 0.f;
  #pragma unroll
  for(int i=0;i<4;i++){ v[i] = ldf(xr[tid + i*256]); ss += v[i]*v[i]; }
  __shared__ float red[256];
  red[tid] = ss; __syncthreads();
  for(int st=128; st>0; st>>=1){ if(tid<st) red[tid] += red[tid+st]; __syncthreads(); }
  float r = rsqrtf(red[0]*(1.f/(float)D_) + 1e-5f);
  #pragma unroll
  for(int i=0;i<4;i++){
    int d = tid + i*256;
    out[(size_t)t*D_ + d] = v[i]*r*ldf(g[d]);
  }
}

// =====================================================================
// Unified MFMA GEMM: C = A @ B  (A: M x K, dtype TA;  B: K x N, dtype TB)
// 128x128 tile, BK=32, 4 waves, mfma_f32_16x16x32_bf16, fp32 accum.
// AMAP: 0 dense row, 1 base+row (contig), 2 gather via list>>1
// OMODE: 0 f32 store, 1 f32 store + resid(TB), 2 bf16 scatter via list,
//        3 f32 accumulate (dense), 4 bf16 store (base+row)
// Expert mode iff cnt != nullptr: M=cnt[e], base=offs[e], B += e*K*N.
// =====================================================================
#define ASTRIDE 40   // shorts per LDS row (80B, 16B-aligned, 2-way banks)

static __device__ __forceinline__ f32x4 mfma16(short8v a, short8v b, f32x4 c){
  return __builtin_amdgcn_mfma_f32_16x16x32_bf16(a, b, c, 0, 0, 0);
}

template<typename TA, typename TB, int AMAP, int OMODE>
__global__ __launch_bounds__(256) void k_mgemm(
    const TA* __restrict__ A, const TB* __restrict__ Bw, void* __restrict__ Cout,
    const TB* __restrict__ resid,
    int M, int N, int K, int ldc,
    const int* __restrict__ cnt, const int* __restrict__ offs, const int* __restrict__ list,
    const int* __restrict__ flag, int want)
{
  if(flag[0] != want) return;
  int e = blockIdx.z;
  int base = 0;
  if(cnt){
    M = cnt[e]; if(M < 0) M = 0; if(M > NT_) M = NT_;
    base = offs[e];
    Bw += (size_t)e * (size_t)K * (size_t)N;
  }
  int m0 = blockIdx.y*128; if(m0 >= M) return;
  int n0 = blockIdx.x*128;

  __shared__ short As[128*ASTRIDE];
  __shared__ short Bs[128*ASTRIDE];   // [col][k]
  __shared__ int rowA[128];

  int tid = threadIdx.x;
  int w = tid>>6, l = tid&63;
  int wr = w>>1, wc = w&1;
  int lr = l&15, lg = l>>4;

  if(tid < 128){
    int rloc = m0 + tid;
    int ar = -1;
    if(rloc < M){
      if(AMAP==2) ar = list[e*NT_ + rloc] >> 1;
      else if(AMAP==1) ar = base + rloc;
      else ar = rloc;
    }
    rowA[tid] = ar;
  }

  f32x4 acc[4][4] = {};

  int KT = (K + 31) >> 5;
  int srow = tid>>1, skh = (tid&1)*16;       // A staging: row, k-half
  int bk = tid>>3, bnc = (tid&7)*16;         // B staging: k, col-seg
  for(int kt = 0; kt < KT; ++kt){
    int k0 = kt*32;
    __syncthreads();
    // ---- stage A tile (128 x 32) as bf16, vectorized fast path ----
    {
      int ar = rowA[srow];
      short tmp[16];
      if(ar >= 0 && k0 + skh + 16 <= K){
        const TA* src = A + (size_t)ar*K + k0 + skh;
        if constexpr (sizeof(TA)==2){
          #pragma unroll
          for(int c=0;c<4;c++) *(short4v*)&tmp[c*4] = ((const short4v*)src)[c];
        } else {
          #pragma unroll
          for(int c=0;c<4;c++){
            f32x4 f = ((const f32x4*)src)[c];
            #pragma unroll
            for(int i=0;i<4;i++) tmp[c*4+i] = f2bs(f[i]);
          }
        }
      } else {
        #pragma unroll
        for(int i=0;i<16;i++){
          int gk = k0 + skh + i;
          float v = 0.f;
          if(ar >= 0 && gk < K) v = ldf(A[(size_t)ar*K + gk]);
          tmp[i] = f2bs(v);
        }
      }
      short8v v0, v1;
      #pragma unroll
      for(int i=0;i<8;i++){ v0[i] = tmp[i]; v1[i] = tmp[8+i]; }
      *(short8v*)&As[srow*ASTRIDE + skh]     = v0;
      *(short8v*)&As[srow*ASTRIDE + skh + 8] = v1;
    }
    // ---- stage B tile (32 x 128) transposed: Bs[col][k], vectorized fast path ----
    {
      int gk = k0 + bk;
      short tmp[16];
      if(gk < K && n0 + bnc + 16 <= N){
        const TB* src = Bw + (size_t)gk*N + n0 + bnc;
        if constexpr (sizeof(TB)==2){
          #pragma unroll
          for(int c=0;c<4;c++) *(short4v*)&tmp[c*4] = ((const short4v*)src)[c];
        } else {
          #pragma unroll
          for(int c=0;c<4;c++){
            f32x4 f = ((const f32x4*)src)[c];
            #pragma unroll
            for(int i=0;i<4;i++) tmp[c*4+i] = f2bs(f[i]);
          }
        }
      } else {
        #pragma unroll
        for(int i=0;i<16;i++){
          int gn = n0 + bnc + i;
          float v = 0.f;
          if(gk < K && gn < N) v = ldf(Bw[(size_t)gk*N + gn]);
          tmp[i] = f2bs(v);
        }
      }
      #pragma unroll
      for(int i=0;i<16;i++) Bs[(bnc+i)*ASTRIDE + bk] = tmp[i];
    }
    __syncthreads();
    // ---- fragments + MFMA (verified layout) ----
    short8v a[4], b[4];
    #pragma unroll
    for(int f=0; f<4; f++){
      a[f] = *(const short8v*)&As[(wr*64 + f*16 + lr)*ASTRIDE + lg*8];
      b[f] = *(const short8v*)&Bs[(wc*64 + f*16 + lr)*ASTRIDE + lg*8];
    }
    #pragma unroll
    for(int fi=0;fi<4;fi++)
      #pragma unroll
      for(int fj=0;fj<4;fj++)
        acc[fi][fj] = mfma16(a[fi], b[fj], acc[fi][fj]);
  }

  // ---- store: frag (fi,fj), lane l -> row = lg*4+r, col = lr ----
  #pragma unroll
  for(int fi=0;fi<4;fi++){
    #pragma unroll
    for(int r=0;r<4;r++){
      int rl = m0 + wr*64 + fi*16 + lg*4 + r;
      if(rl >= M) continue;
      int orow;
      if(OMODE==2){ orow = list[e*NT_ + rl]; if(orow < 0 || orow >= 2*NT_) continue; }
      else orow = base + rl;
      #pragma unroll
      for(int fj=0;fj<4;fj++){
        int gcol = n0 + wc*64 + fj*16 + lr;
        if(gcol >= N) continue;
        float v = acc[fi][fj][r];
        size_t o = (size_t)orow*ldc + gcol;
        if(OMODE==0)      ((float*)Cout)[o] = v;
        else if(OMODE==1) ((float*)Cout)[o] = v + ldf(resid[o]);
        else if(OMODE==2) ((bf16*)Cout)[o] = f2b(v);
        else if(OMODE==3) ((float*)Cout)[o] = ((float*)Cout)[o] + v;
        else              ((bf16*)Cout)[o] = f2b(v);
      }
    }
  }
}

// ---------------- silu(t1)*t3 elementwise, bf16 ----------------
__global__ __launch_bounds__(256) void k_silu(const bf16* __restrict__ t1, const bf16* __restrict__ t3,
                                              bf16* __restrict__ out, int n4){
  int i = blockIdx.x*256 + threadIdx.x;
  if(i >= n4) return;
  #pragma unroll
  for(int j=0;j<4;j++){
    int idx = i*4 + j;
    float a = b2f(t1[idx]);
    out[idx] = f2b((a/(1.f+expf(-a))) * b2f(t3[idx]));
  }
}

// ---------------- RoPE in-place on bf16 q (4096x1024) and k (4096x256) ----------------
template<typename TF>
__global__ __launch_bounds__(256) void k_rope(bf16* __restrict__ ql, bf16* __restrict__ kl,
                                              const TF* __restrict__ fc, const TF* __restrict__ fs,
                                              const int* __restrict__ flag, int want){
  if(flag[0] != want) return;
  int t = blockIdx.x; int s = t % S_;
  int tid = threadIdx.x;
  for(int p0 = tid; p0 < 512; p0 += 256){
    int h = p0>>5, p = p0&31;
    float c = ldf(fc[s*32+p]), sn = ldf(fs[s*32+p]);
    size_t o = (size_t)t*D_ + h*64 + 2*p;
    float xr = b2f(ql[o]), xi = b2f(ql[o+1]);
    ql[o]   = f2b(xr*c - xi*sn);
    ql[o+1] = f2b(xr*sn + xi*c);
  }
  if(tid < 128){
    int h = tid>>5, p = tid&31;
    float c = ldf(fc[s*32+p]), sn = ldf(fs[s*32+p]);
    size_t o = (size_t)t*256 + h*64 + 2*p;
    float xr = b2f(kl[o]), xi = b2f(kl[o+1]);
    kl[o]   = f2b(xr*c - xi*sn);
    kl[o+1] = f2b(xr*sn + xi*c);
  }
}

// ---------------- MFMA flash attention, bf16 in/out ----------------
// Per block: 64 q-rows, loop over 64-row kv tiles. 4 waves x 16 q-rows each.
// Uses the round-6-verified fragment idiom: A-frag row = lane&15, k = (lane>>4)*8;
// C/D: col = lane&15, row = (lane>>4)*4 + reg.
#define TST 72   // shorts per LDS row: 144B, keeps ds_read_b128 16B-aligned

__global__ __launch_bounds__(256) void k_attn(const bf16* __restrict__ Q, const bf16* __restrict__ Kg,
                                              const bf16* __restrict__ V, bf16* __restrict__ Out){
  int qt_ = (S_/64 - 1) - blockIdx.x;
  int h = blockIdx.y, b = blockIdx.z;
  int kvh = h>>2;
  const bf16* qb = Q + (size_t)b*S_*D_ + h*HD_;        // row stride D_
  const bf16* kb = Kg + (size_t)b*S_*256 + kvh*HD_;    // row stride 256
  const bf16* vb = V  + (size_t)b*S_*256 + kvh*HD_;
  __shared__ short Qs[64*TST];
  __shared__ short Ks[64*TST];
  __shared__ short Vt[64*TST];          // V transposed: Vt[d][kv]
  __shared__ short Ps[4][16*TST];       // per-wave P tile (16 q-rows x 64 kv)
  int tid = threadIdx.x;
  int w = tid>>6, l = tid&63, lr = l&15, lg = l>>4;
  int sr = tid>>2, sc0 = (tid&3)*16;    // staging: row, col-run of 16

  // stage Q once (scale folded later into scores)
  {
    const short8v* src = (const short8v*)(qb + (size_t)(qt_*64 + sr)*D_ + sc0);
    *(short8v*)&Qs[sr*TST + sc0]     = src[0];
    *(short8v*)&Qs[sr*TST + sc0 + 8] = src[1];
  }
  __syncthreads();
  short8v aQ0 = *(const short8v*)&Qs[(w*16+lr)*TST + lg*8];
  short8v aQ1 = *(const short8v*)&Qs[(w*16+lr)*TST + lg*8 + 32];

  float mreg[4], lreg[4];
  f32x4 accO[4] = {};
  #pragma unroll
  for(int r=0;r<4;r++){ mreg[r] = NEGBIG; lreg[r] = 0.f; }

  for(int kt=0; kt<=qt_; ++kt){
    __syncthreads();   // all waves done reading Ks/Vt from previous iter
    {
      const short8v* ksrc = (const short8v*)(kb + (size_t)(kt*64 + sr)*256 + sc0);
      *(short8v*)&Ks[sr*TST + sc0]     = ksrc[0];
      *(short8v*)&Ks[sr*TST + sc0 + 8] = ksrc[1];
      const short8v* vsrc = (const short8v*)(vb + (size_t)(kt*64 + sr)*256 + sc0);
      short8v v0 = vsrc[0], v1 = vsrc[1];
      #pragma unroll
      for(int i=0;i<8;i++){
        Vt[(sc0+i)*TST + sr]   = v0[i];
        Vt[(sc0+8+i)*TST + sr] = v1[i];
      }
    }
    __syncthreads();
    // ---- QK^T: S[q=w*16+lg*4+r][kcol=fj*16+lr] ----
    f32x4 s[4];
    #pragma unroll
    for(int fj=0; fj<4; fj++){
      short8v b0 = *(const short8v*)&Ks[(fj*16+lr)*TST + lg*8];
      short8v b1 = *(const short8v*)&Ks[(fj*16+lr)*TST + lg*8 + 32];
      f32x4 z = {};
      z = mfma16(aQ0, b0, z);
      z = mfma16(aQ1, b1, z);
      s[fj] = z;
    }
    #pragma unroll
    for(int fj=0; fj<4; fj++)
      #pragma unroll
      for(int r=0;r<4;r++){
        float v = s[fj][r]*0.125f;                       // 1/sqrt(64)
        if(kt==qt_ && (fj*16+lr) > (w*16+lg*4+r)) v = NEGBIG;
        s[fj][r] = v;
      }
    // ---- online softmax (row spread across 16 lr-lanes x 4 fj) ----
    float p[4][4], sc[4];
    #pragma unroll
    for(int r=0;r<4;r++){
      float mx = fmaxf(fmaxf(s[0][r],s[1][r]), fmaxf(s[2][r],s[3][r]));
      mx = fmaxf(mx, __shfl_xor(mx,1,64));
      mx = fmaxf(mx, __shfl_xor(mx,2,64));
      mx = fmaxf(mx, __shfl_xor(mx,4,64));
      mx = fmaxf(mx, __shfl_xor(mx,8,64));
      float mn = fmaxf(mreg[r], mx);
      sc[r] = expf(mreg[r]-mn);
      float ps = 0.f;
      #pragma unroll
      for(int fj=0;fj<4;fj++){ float pv = expf(s[fj][r]-mn); p[fj][r] = pv; ps += pv; }
      ps += __shfl_xor(ps,1,64); ps += __shfl_xor(ps,2,64);
      ps += __shfl_xor(ps,4,64); ps += __shfl_xor(ps,8,64);
      lreg[r] = lreg[r]*sc[r] + ps;
      mreg[r] = mn;
    }
    #pragma unroll
    for(int fj=0;fj<4;fj++)
      #pragma unroll
      for(int r=0;r<4;r++)
        accO[fj][r] *= sc[r];
    // ---- P -> bf16 -> per-wave LDS ----
    #pragma unroll
    for(int fj=0;fj<4;fj++)
      #pragma unroll
      for(int r=0;r<4;r++)
        Ps[w][(lg*4+r)*TST + fj*16+lr] = f2bs(p[fj][r]);
    __syncthreads();   // uniform; guarantees P visible before frag reads
    // ---- PV: O[q][d=fj*16+lr] += P[q][kv] @ V[kv][d] ----
    short8v a0 = *(const short8v*)&Ps[w][lr*TST + lg*8];
    short8v a1 = *(const short8v*)&Ps[w][lr*TST + lg*8 + 32];
    #pragma unroll
    for(int fj=0;fj<4;fj++){
      short8v b0 = *(const short8v*)&Vt[(fj*16+lr)*TST + lg*8];
      short8v b1 = *(const short8v*)&Vt[(fj*16+lr)*TST + lg*8 + 32];
      accO[fj] = mfma16(a0, b0, accO[fj]);
      accO[fj] = mfma16(a1, b1, accO[fj]);
    }
  }
  // epilogue: Out layout [t][h*64+d]
  #pragma unroll
  for(int r=0;r<4;r++){
    int qr = qt_*64 + w*16 + lg*4 + r;
    float inv = (lreg[r] > 0.f) ? 1.f/lreg[r] : 0.f;
    #pragma unroll
    for(int fj=0;fj<4;fj++)
      Out[((size_t)(b*S_+qr))*D_ + h*HD_ + fj*16+lr] = f2b(accO[fj][r]*inv);
  }
}

// ---------------- Router: one wave per token, f32 x ----------------
template<typename TW>
__global__ __launch_bounds__(64) void k_router(const float* __restrict__ X, const TW* __restrict__ W,
                                               float* __restrict__ probs, float* __restrict__ p01,
                                               int* __restrict__ idx0buf, int* __restrict__ list,
                                               int* __restrict__ cnt, const int* __restrict__ flag, int want){
  if(flag[0] != want) return;
  int t = blockIdx.x; int lane = threadIdx.x;
  float pe[8] = {};
  for(int d = lane; d < D_; d += 64){
    float xv = X[(size_t)t*D_ + d];
    const TW* wr = W + (size_t)d*E_;
    #pragma unroll
    for(int e=0;e<8;e++) pe[e] += xv*ldf(wr[e]);
  }
  for(int msk=1;msk<64;msk<<=1)
    #pragma unroll
    for(int e=0;e<8;e++) pe[e] += __shfl_xor(pe[e], msk, 64);
  if(lane == 0){
    float mx = pe[0];
    #pragma unroll
    for(int e=1;e<8;e++) mx = fmaxf(mx, pe[e]);
    float pr[8], sum = 0.f;
    #pragma unroll
    for(int e=0;e<8;e++){ pr[e] = expf(pe[e]-mx); sum += pr[e]; }
    #pragma unroll
    for(int e=0;e<8;e++){ pr[e] /= sum; probs[t*8+e] = pr[e]; }
    int i0 = 0;
    #pragma unroll
    for(int e=1;e<8;e++) if(pe[e] > pe[i0]) i0 = e;
    int i1 = -1;
    #pragma unroll
    for(int e=0;e<8;e++){ if(e==i0) continue; if(i1<0 || pe[e] > pe[i1]) i1 = e; }
    p01[t*2]   = pr[i0];
    p01[t*2+1] = pr[i1];
    idx0buf[t] = i0;
    int pos = atomicAdd(&cnt[i0], 1);
    if(pos >= 0 && pos < NT_) list[i0*NT_ + pos] = t*2;
    pos     = atomicAdd(&cnt[i1], 1);
    if(pos >= 0 && pos < NT_) list[i1*NT_ + pos] = t*2 + 1;
  }
}

__global__ __launch_bounds__(256) void k_stats(const float* __restrict__ probs, const int* __restrict__ idx0buf,
                                               float* __restrict__ cnt0f, float* __restrict__ psum){
  int e = blockIdx.x; int tid = threadIdx.x;
  float sp = 0.f, sc = 0.f;
  for(int n = tid; n < NT_; n += 256){ sp += probs[n*8+e]; sc += (idx0buf[n]==e) ? 1.f : 0.f; }
  __shared__ float r1[256], r2[256];
  r1[tid] = sp; r2[tid] = sc; __syncthreads();
  for(int st=128; st>0; st>>=1){ if(tid<st){ r1[tid]+=r1[tid+st]; r2[tid]+=r2[tid+st]; } __syncthreads(); }
  if(tid==0){ psum[e] = r1[0]; cnt0f[e] = r2[0]; }
}

__global__ void k_finish(const float* __restrict__ cnt0f, const float* __restrict__ psum,
                         const int* __restrict__ cnt, int* __restrict__ offs,
                         bf16* __restrict__ auxb, float* __restrict__ auxf, const int* __restrict__ flag){
  if(threadIdx.x==0 && blockIdx.x==0){
    int o = 0;
    for(int e=0;e<8;e++){ offs[e] = o; int c = cnt[e]; if(c < 0) c = 0; if(c > NT_) c = NT_; o += c; }
    float aux = 0.f;
    for(int e=0;e<8;e++) aux += (cnt0f[e]*(1.f/(float)NT_))*(psum[e]*(1.f/(float)NT_));
    float v = aux*0.01f*8.f;
    if(flag[0]) auxb[0] = f2b(v); else auxf[0] = v;
  }
}

// ---------------- Combine: out = h(+shared) + p0*eo0 + p1*eo1 ----------------
__global__ __launch_bounds__(256) void k_combine(const float* __restrict__ hbuf, const bf16* __restrict__ eosl,
                                                 const float* __restrict__ p01,
                                                 bf16* __restrict__ outb, float* __restrict__ outf,
                                                 const int* __restrict__ flag){
  int t = blockIdx.x; int tid = threadIdx.x;
  int isbf = flag[0];
  float p0 = p01[t*2], p1 = p01[t*2+1];
  #pragma unroll
  for(int i=0;i<4;i++){
    int d = tid + i*256;
    float v = hbuf[(size_t)t*D_ + d]
            + p0*b2f(eosl[((size_t)(t*2))*D_ + d])
            + p1*b2f(eosl[((size_t)(t*2+1))*D_ + d]);
    size_t o = (size_t)t*D_ + d;
    if(isbf) outb[o] = f2b(v); else outf[o] = v;
  }
}

// ---------------- workspace layout (bytes) ----------------
// qlin/klin/vlin/aout now bf16 (half their old slots; offsets unchanged).
static const size_t O_HBUF = 0;          // f32 4096x1024 (xn slot first, then hbuf)
static const size_t O_XN   = 0;          // f32, dead after QKV gemms
static const size_t O_QLIN = 16777216;   // bf16 4096x1024 -> 25165824
static const size_t O_KLIN = 33554432;   // bf16 4096x256  -> 35651584
static const size_t O_VLIN = 37748736;   // bf16 4096x256  -> 39845888
static const size_t O_AOUT = 41943040;   // bf16 4096x1024 -> 50331648 (dead before SHH use)
// Phase B (order: eff1 -> silu(expert) -> sff1 -> silu(shared) -> ffn2s):
static const size_t O_XN2  = 16777216;   // f32 4096x1024 (over QLIN, dead)
static const size_t O_T1E  = 33554432;   // bf16 8192x684 -> 44761088
static const size_t O_T3E  = 44761088;   // bf16 8192x684 -> 55967744
static const size_t O_HEXP = 55967744;   // bf16 8192x684 -> 67174400
static const size_t O_T1S  = 33554432;   // bf16 4096x684 (over T1E, dead after expert silu)
static const size_t O_T3S  = 39157760;   // bf16 4096x684
static const size_t O_SHH  = 44761088;   // bf16 4096x684 (over T3E, dead after expert silu)
static const size_t O_EOSL = 16777216;   // bf16 8192x1024 (over XN2, dead after ffn1s)
// control block:
static const size_t O_PROBS= 67174400;
static const size_t O_P01  = 67305472;
static const size_t O_IDX0 = 67338240;
static const size_t O_LIST = 67354624;
static const size_t O_CNT  = 67485696;
static const size_t O_CNT0 = 67485728;
static const size_t O_PSUM = 67485760;
static const size_t O_OFFS = 67485792;
static const size_t O_FLAG = 67485824;

extern "C" void kernel_launch(void* const* d_in, const int* in_sizes, int n_in,
                              void* d_out, int out_size, void* d_ws, size_t ws_size,
                              hipStream_t stream){
  (void)in_sizes; (void)n_in; (void)out_size; (void)ws_size;
  char* ws = (char*)d_ws;
  float* xn   = (float*)(ws + O_XN);
  bf16* qlin  = (bf16*)(ws + O_QLIN);
  bf16* klin  = (bf16*)(ws + O_KLIN);
  bf16* vlin  = (bf16*)(ws + O_VLIN);
  bf16* aout  = (bf16*)(ws + O_AOUT);
  float* hbuf = (float*)(ws + O_HBUF);
  float* xn2  = (float*)(ws + O_XN2);
  bf16* t1e   = (bf16*)(ws + O_T1E);
  bf16* t3e   = (bf16*)(ws + O_T3E);
  bf16* hexp  = (bf16*)(ws + O_HEXP);
  bf16* t1s   = (bf16*)(ws + O_T1S);
  bf16* t3s   = (bf16*)(ws + O_T3S);
  bf16* shh   = (bf16*)(ws + O_SHH);
  bf16* eosl  = (bf16*)(ws + O_EOSL);
  float* probs=(float*)(ws + O_PROBS);
  float* p01 = (float*)(ws + O_P01);
  int*  idx0 = (int*)(ws + O_IDX0);
  int*  list = (int*)(ws + O_LIST);
  int*  cnt  = (int*)(ws + O_CNT);
  float* cnt0f=(float*)(ws + O_CNT0);
  float* psum= (float*)(ws + O_PSUM);
  int*  offs = (int*)(ws + O_OFFS);
  int*  flg  = (int*)(ws + O_FLAG);

  bf16* outb = (bf16*)d_out;
  float* outf = (float*)d_out;
  bf16* auxb = outb + (size_t)NT_*D_;
  float* auxf = outf + (size_t)NT_*D_;

  k_detect<<<1, 64, 0, stream>>>((const uint32_t*)d_in[14], flg, cnt);

  // ---- attention block ----
  k_rms<bf16,bf16>  <<<NT_, 256, 0, stream>>>((const bf16*)d_in[0], (const bf16*)d_in[14], xn, flg, 1);
  k_rms<float,float><<<NT_, 256, 0, stream>>>((const float*)d_in[0], (const float*)d_in[14], xn, flg, 0);

  // QKV gemms -> bf16 outputs
  k_mgemm<float,bf16,0,4> <<<dim3(8,32), 256, 0, stream>>>(xn, (const bf16*)d_in[3], qlin, nullptr, NT_, D_, D_, D_, nullptr, nullptr, nullptr, flg, 1);
  k_mgemm<float,float,0,4><<<dim3(8,32), 256, 0, stream>>>(xn, (const float*)d_in[3], qlin, nullptr, NT_, D_, D_, D_, nullptr, nullptr, nullptr, flg, 0);
  k_mgemm<float,bf16,0,4> <<<dim3(2,32), 256, 0, stream>>>(xn, (const bf16*)d_in[4], klin, nullptr, NT_, 256, D_, 256, nullptr, nullptr, nullptr, flg, 1);
  k_mgemm<float,float,0,4><<<dim3(2,32), 256, 0, stream>>>(xn, (const float*)d_in[4], klin, nullptr, NT_, 256, D_, 256, nullptr, nullptr, nullptr, flg, 0);
  k_mgemm<float,bf16,0,4> <<<dim3(2,32), 256, 0, stream>>>(xn, (const bf16*)d_in[5], vlin, nullptr, NT_, 256, D_, 256, nullptr, nullptr, nullptr, flg, 1);
  k_mgemm<float,float,0,4><<<dim3(2,32), 256, 0, stream>>>(xn, (const float*)d_in[5], vlin, nullptr, NT_, 256, D_, 256, nullptr, nullptr, nullptr, flg, 0);

  k_rope<bf16> <<<NT_, 256, 0, stream>>>(qlin, klin, (const bf16*)d_in[1], (const bf16*)d_in[2], flg, 1);
  k_rope<float><<<NT_, 256, 0, stream>>>(qlin, klin, (const float*)d_in[1], (const float*)d_in[2], flg, 0);

  k_attn<<<dim3(S_/64, H_, B_), 256, 0, stream>>>(qlin, klin, vlin, aout);

  // wo + residual -> hbuf (overlays xn, dead now)
  k_mgemm<bf16,bf16,0,1> <<<dim3(8,32), 256, 0, stream>>>(aout, (const bf16*)d_in[6], hbuf, (const bf16*)d_in[0], NT_, D_, D_, D_, nullptr, nullptr, nullptr, flg, 1);
  k_mgemm<bf16,float,0,1><<<dim3(8,32), 256, 0, stream>>>(aout, (const float*)d_in[6], hbuf, (const float*)d_in[0], NT_, D_, D_, D_, nullptr, nullptr, nullptr, flg, 0);

  // ---- MoE block ----
  k_rms<float,bf16> <<<NT_, 256, 0, stream>>>(hbuf, (const bf16*)d_in[15], xn2, flg, 1);
  k_rms<float,float><<<NT_, 256, 0, stream>>>(hbuf, (const float*)d_in[15], xn2, flg, 0);

  k_router<bf16> <<<NT_, 64, 0, stream>>>(xn2, (const bf16*)d_in[7], probs, p01, idx0, list, cnt, flg, 1);
  k_router<float><<<NT_, 64, 0, stream>>>(xn2, (const float*)d_in[7], probs, p01, idx0, list, cnt, flg, 0);

  k_stats<<<E_, 256, 0, stream>>>(probs, idx0, cnt0f, psum);
  k_finish<<<1, 64, 0, stream>>>(cnt0f, psum, cnt, offs, auxb, auxf, flg);

  // expert ffn1
  k_mgemm<float,bf16,2,4> <<<dim3(6,32,E_), 256, 0, stream>>>(xn2, (const bf16*)d_in[8], t1e, nullptr, 0, HIDDEN_, D_, HIDDEN_, cnt, offs, list, flg, 1);
  k_mgemm<float,float,2,4><<<dim3(6,32,E_), 256, 0, stream>>>(xn2, (const float*)d_in[8], t1e, nullptr, 0, HIDDEN_, D_, HIDDEN_, cnt, offs, list, flg, 0);
  k_mgemm<float,bf16,2,4> <<<dim3(6,32,E_), 256, 0, stream>>>(xn2, (const bf16*)d_in[10], t3e, nullptr, 0, HIDDEN_, D_, HIDDEN_, cnt, offs, list, flg, 1);
  k_mgemm<float,float,2,4><<<dim3(6,32,E_), 256, 0, stream>>>(xn2, (const float*)d_in[10], t3e, nullptr, 0, HIDDEN_, D_, HIDDEN_, cnt, offs, list, flg, 0);

  // expert silu FIRST (t1e/t3e die here)
  k_silu<<<(2*NT_*HIDDEN_/4 + 255)/256, 256, 0, stream>>>(t1e, t3e, hexp, 2*NT_*HIDDEN_/4);

  // shared ffn1 (overlays t1e/t3e — legal now)
  k_mgemm<float,bf16,0,4> <<<dim3(6,32), 256, 0, stream>>>(xn2, (const bf16*)d_in[11], t1s, nullptr, NT_, HIDDEN_, D_, HIDDEN_, nullptr, nullptr, nullptr, flg, 1);
  k_mgemm<float,float,0,4><<<dim3(6,32), 256, 0, stream>>>(xn2, (const float*)d_in[11], t1s, nullptr, NT_, HIDDEN_, D_, HIDDEN_, nullptr, nullptr, nullptr, flg, 0);
  k_mgemm<float,bf16,0,4> <<<dim3(6,32), 256, 0, stream>>>(xn2, (const bf16*)d_in[13], t3s, nullptr, NT_, HIDDEN_, D_, HIDDEN_, nullptr, nullptr, nullptr, flg, 1);
  k_mgemm<float,float,0,4><<<dim3(6,32), 256, 0, stream>>>(xn2, (const float*)d_in[13], t3s, nullptr, NT_, HIDDEN_, D_, HIDDEN_, nullptr, nullptr, nullptr, flg, 0);

  k_silu<<<(NT_*HIDDEN_/4 + 255)/256, 256, 0, stream>>>(t1s, t3s, shh, NT_*HIDDEN_/4);

  // expert ffn2 (scatter; overlays xn2 — dead now)
  k_mgemm<bf16,bf16,1,2> <<<dim3(8,32,E_), 256, 0, stream>>>(hexp, (const bf16*)d_in[9], eosl, nullptr, 0, D_, HIDDEN_, D_, cnt, offs, list, flg, 1);
  k_mgemm<bf16,float,1,2><<<dim3(8,32,E_), 256, 0, stream>>>(hexp, (const float*)d_in[9], eosl, nullptr, 0, D_, HIDDEN_, D_, cnt, offs, list, flg, 0);
  // shared ffn2: hbuf += shh @ sw2
  k_mgemm<bf16,bf16,0,3> <<<dim3(8,32), 256, 0, stream>>>(shh, (const bf16*)d_in[12], hbuf, nullptr, NT_, D_, HIDDEN_, D_, nullptr, nullptr, nullptr, flg, 1);
  k_mgemm<bf16,float,0,3><<<dim3(8,32), 256, 0, stream>>>(shh, (const float*)d_in[12], hbuf, nullptr, NT_, D_, HIDDEN_, D_, nullptr, nullptr, nullptr, flg, 0);

  k_combine<<<NT_, 256, 0, stream>>>(hbuf, eosl, p01, outb, outf, flg);
}

// Round 8
// 1081.619 us; speedup vs baseline: 3.0514x; 1.1101x over previous
//
#include <hip/hip_runtime.h>
#include <hip/hip_bf16.h>
#include <cstdint>

#define B_ 2
#define S_ 2048
#define D_ 1024
#define H_ 16
#define HKV_ 4
#define HD_ 64
#define E_ 8
#define HIDDEN_ 684
#define NT_ (B_*S_)
#define NEGBIG (-1e30f)

using bf16 = __hip_bfloat16;
typedef __attribute__((ext_vector_type(8))) short short8v;
typedef __attribute__((ext_vector_type(4))) short short4v;
typedef __attribute__((ext_vector_type(4))) float f32x4;

static __device__ __forceinline__ float b2f(bf16 v){ return __bfloat162float(v); }
static __device__ __forceinline__ bf16 f2b(float v){ return __float2bfloat16(v); }
static __device__ __forceinline__ short f2bs(float v){ bf16 h = f2b(v); return *reinterpret_cast<short*>(&h); }
static __device__ __forceinline__ float dload(const void* p, size_t i, int isbf){
  return isbf ? b2f(((const bf16*)p)[i]) : ((const float*)p)[i];
}

__global__ void k_detect(const uint32_t* __restrict__ g, int* __restrict__ flag, int* __restrict__ cnt){
  if(threadIdx.x == 0 && blockIdx.x == 0){
    uint32_t w0 = g[0], w1 = g[1], w2 = g[2], w3 = g[3];
    int bf;
    if(w0==0x3F803F80u && w1==0x3F803F80u && w2==0x3F803F80u && w3==0x3F803F80u) bf = 1;
    else if(w0==0x3F800000u && w1==0x3F800000u && w2==0x3F800000u && w3==0x3F800000u) bf = 0;
    else bf = 1;
    flag[0] = bf;
  }
  if(threadIdx.x < E_ && blockIdx.x == 0) cnt[threadIdx.x] = 0;
}

// ---------------- RMSNorm -> f32 out ----------------
__global__ __launch_bounds__(256) void k_rms(const void* __restrict__ X, const void* __restrict__ g,
                                             float* __restrict__ out, const int* __restrict__ flag, int xdyn){
  int isbf = flag[0]; int xb = xdyn ? isbf : 0;
  int t = blockIdx.x; int tid = threadIdx.x;
  float v[4]; float ss = 0.f;
  #pragma unroll
  for(int i=0;i<4;i++){ v[i] = dload(X, (size_t)t*D_ + tid + i*256, xb); ss += v[i]*v[i]; }
  __shared__ float red[256];
  red[tid] = ss; __syncthreads();
  for(int st=128; st>0; st>>=1){ if(tid<st) red[tid] += red[tid+st]; __syncthreads(); }
  float r = rsqrtf(red[0]*(1.f/(float)D_) + 1e-5f);
  #pragma unroll
  for(int i=0;i<4;i++){
    int d = tid + i*256;
    out[(size_t)t*D_ + d] = v[i]*r*dload(g, d, isbf);
  }
}

// =====================================================================
// Unified MFMA GEMM. A typed (internal). B runtime-dtype (weights, void*).
// 128x128 tile, BK=32, XOR k-block swizzle: phys = logical ^ ((row>>4)&3).
// AMAP: 0 = base+rloc (dense/contig), 2 = gather via list>>1
// OMODE: 1 f32 + resid(dyn), 2 bf16 scatter via list, 3 f32 accumulate, 4 bf16 store
// Expert mode iff cnt != nullptr.
// =====================================================================
#define ASTRIDE 40

static __device__ __forceinline__ f32x4 mfma16(short8v a, short8v b, f32x4 c){
  return __builtin_amdgcn_mfma_f32_16x16x32_bf16(a, b, c, 0, 0, 0);
}

template<typename TA, int AMAP, int OMODE>
__global__ __launch_bounds__(256) void k_mgemm(
    const TA* __restrict__ A, const void* __restrict__ Bw, void* __restrict__ Cout,
    const void* __restrict__ resid,
    int M, int N, int K, int ldc,
    const int* __restrict__ cnt, const int* __restrict__ offs, const int* __restrict__ list,
    const int* __restrict__ flag)
{
  int isbf = flag[0];
  int e = blockIdx.z;
  int base = 0; size_t eoff = 0;
  if(cnt){
    M = cnt[e]; if(M < 0) M = 0; if(M > NT_) M = NT_;
    base = offs[e];
    eoff = (size_t)e * (size_t)K * (size_t)N;
  }
  int m0 = blockIdx.y*128; if(m0 >= M) return;
  int n0 = blockIdx.x*128;

  __shared__ short As[128*ASTRIDE];
  __shared__ short Bs[128*ASTRIDE];
  __shared__ int rowA[128];

  int tid = threadIdx.x;
  int w = tid>>6, l = tid&63;
  int wr = w>>1, wc = w&1;
  int lr = l&15, lg = l>>4;

  if(tid < 128){
    int rloc = m0 + tid;
    int ar = -1;
    if(rloc < M){
      if(AMAP==2) ar = list[e*NT_ + rloc] >> 1;
      else ar = base + rloc;
    }
    rowA[tid] = ar;
  }

  f32x4 acc[4][4] = {};

  int KT = (K + 31) >> 5;
  int srow = tid>>1, skh = (tid&1)*16;
  int keya = (srow>>4)&3, kb0 = skh>>3;
  int bk = tid>>3, bnc = (tid&7)*16;
  int keyb = tid&3;
  int bkb = bk>>3, bkw = bk&7;
  for(int kt = 0; kt < KT; ++kt){
    int k0 = kt*32;
    __syncthreads();
    // ---- stage A (128x32) bf16, vectorized, swizzled write ----
    {
      int ar = rowA[srow];
      short tmp[16];
      if(ar >= 0 && k0 + skh + 16 <= K){
        const TA* src = A + (size_t)ar*K + k0 + skh;
        if constexpr (sizeof(TA)==2){
          #pragma unroll
          for(int c=0;c<4;c++) *(short4v*)&tmp[c*4] = ((const short4v*)src)[c];
        } else {
          #pragma unroll
          for(int c=0;c<4;c++){
            f32x4 f = ((const f32x4*)src)[c];
            #pragma unroll
            for(int i=0;i<4;i++) tmp[c*4+i] = f2bs(f[i]);
          }
        }
      } else {
        #pragma unroll
        for(int i=0;i<16;i++){
          int gk = k0 + skh + i;
          float v = 0.f;
          if(ar >= 0 && gk < K){
            if constexpr (sizeof(TA)==2) v = b2f(*(const bf16*)&A[(size_t)ar*K+gk]);
            else v = (float)A[(size_t)ar*K+gk];
          }
          tmp[i] = f2bs(v);
        }
      }
      short8v v0, v1;
      #pragma unroll
      for(int i=0;i<8;i++){ v0[i] = tmp[i]; v1[i] = tmp[8+i]; }
      *(short8v*)&As[srow*ASTRIDE + ((kb0^keya)<<3)]     = v0;
      *(short8v*)&As[srow*ASTRIDE + (((kb0+1)^keya)<<3)] = v1;
    }
    // ---- stage B (32x128) transposed, runtime dtype, swizzled write ----
    {
      int gk = k0 + bk;
      short tmp[16];
      if(gk < K && n0 + bnc + 16 <= N){
        size_t bbase = eoff + (size_t)gk*N + n0 + bnc;
        if(isbf){
          const short4v* src = (const short4v*)((const bf16*)Bw + bbase);
          #pragma unroll
          for(int c=0;c<4;c++) *(short4v*)&tmp[c*4] = src[c];
        } else {
          const f32x4* src = (const f32x4*)((const float*)Bw + bbase);
          #pragma unroll
          for(int c=0;c<4;c++){
            f32x4 f = src[c];
            #pragma unroll
            for(int i=0;i<4;i++) tmp[c*4+i] = f2bs(f[i]);
          }
        }
      } else {
        #pragma unroll
        for(int i=0;i<16;i++){
          int gn = n0 + bnc + i;
          float v = 0.f;
          if(gk < K && gn < N) v = dload(Bw, eoff + (size_t)gk*N + gn, isbf);
          tmp[i] = f2bs(v);
        }
      }
      int bcol = ((bkb^keyb)<<3) + bkw;
      #pragma unroll
      for(int i=0;i<16;i++) Bs[(bnc+i)*ASTRIDE + bcol] = tmp[i];
    }
    __syncthreads();
    short8v a[4], b[4];
    #pragma unroll
    for(int f=0; f<4; f++){
      a[f] = *(const short8v*)&As[(wr*64 + f*16 + lr)*ASTRIDE + ((lg^f)<<3)];
      b[f] = *(const short8v*)&Bs[(wc*64 + f*16 + lr)*ASTRIDE + ((lg^f)<<3)];
    }
    #pragma unroll
    for(int fi=0;fi<4;fi++)
      #pragma unroll
      for(int fj=0;fj<4;fj++)
        acc[fi][fj] = mfma16(a[fi], b[fj], acc[fi][fj]);
  }

  #pragma unroll
  for(int fi=0;fi<4;fi++){
    #pragma unroll
    for(int r=0;r<4;r++){
      int rl = m0 + wr*64 + fi*16 + lg*4 + r;
      if(rl >= M) continue;
      int orow;
      if(OMODE==2){ orow = list[e*NT_ + rl]; if(orow < 0 || orow >= 2*NT_) continue; }
      else orow = base + rl;
      #pragma unroll
      for(int fj=0;fj<4;fj++){
        int gcol = n0 + wc*64 + fj*16 + lr;
        if(gcol >= N) continue;
        float v = acc[fi][fj][r];
        size_t o = (size_t)orow*ldc + gcol;
        if(OMODE==1)      ((float*)Cout)[o] = v + dload(resid, o, isbf);
        else if(OMODE==2) ((bf16*)Cout)[o] = f2b(v);
        else if(OMODE==3) ((float*)Cout)[o] = ((float*)Cout)[o] + v;
        else              ((bf16*)Cout)[o] = f2b(v);
      }
    }
  }
}

__global__ __launch_bounds__(256) void k_silu(const bf16* __restrict__ t1, const bf16* __restrict__ t3,
                                              bf16* __restrict__ out, int n4){
  int i = blockIdx.x*256 + threadIdx.x;
  if(i >= n4) return;
  #pragma unroll
  for(int j=0;j<4;j++){
    int idx = i*4 + j;
    float a = b2f(t1[idx]);
    out[idx] = f2b((a/(1.f+__expf(-a))) * b2f(t3[idx]));
  }
}

__global__ __launch_bounds__(256) void k_rope(bf16* __restrict__ ql, bf16* __restrict__ kl,
                                              const void* __restrict__ fc, const void* __restrict__ fs,
                                              const int* __restrict__ flag){
  int isbf = flag[0];
  int t = blockIdx.x; int s = t % S_;
  int tid = threadIdx.x;
  for(int p0 = tid; p0 < 512; p0 += 256){
    int h = p0>>5, p = p0&31;
    float c = dload(fc, s*32+p, isbf), sn = dload(fs, s*32+p, isbf);
    size_t o = (size_t)t*D_ + h*64 + 2*p;
    float xr = b2f(ql[o]), xi = b2f(ql[o+1]);
    ql[o]   = f2b(xr*c - xi*sn);
    ql[o+1] = f2b(xr*sn + xi*c);
  }
  if(tid < 128){
    int h = tid>>5, p = tid&31;
    float c = dload(fc, s*32+p, isbf), sn = dload(fs, s*32+p, isbf);
    size_t o = (size_t)t*256 + h*64 + 2*p;
    float xr = b2f(kl[o]), xi = b2f(kl[o+1]);
    kl[o]   = f2b(xr*c - xi*sn);
    kl[o+1] = f2b(xr*sn + xi*c);
  }
}

#define TST 72

__global__ __launch_bounds__(256) void k_attn(const bf16* __restrict__ Q, const bf16* __restrict__ Kg,
                                              const bf16* __restrict__ V, bf16* __restrict__ Out){
  int qt_ = (S_/64 - 1) - blockIdx.x;
  int h = blockIdx.y, b = blockIdx.z;
  int kvh = h>>2;
  const bf16* qb = Q + (size_t)b*S_*D_ + h*HD_;
  const bf16* kb = Kg + (size_t)b*S_*256 + kvh*HD_;
  const bf16* vb = V  + (size_t)b*S_*256 + kvh*HD_;
  __shared__ short Qs[64*TST];
  __shared__ short Ks[64*TST];
  __shared__ short Vt[64*TST];
  __shared__ short Ps[4][16*TST];
  int tid = threadIdx.x;
  int w = tid>>6, l = tid&63, lr = l&15, lg = l>>4;
  int sr = tid>>2, sc0 = (tid&3)*16;
  int vc = (((sr>>3)^(tid&3))<<3) + (sr&7);   // kv-block swizzle key = (d>>4)&3 = tid&3

  {
    const short8v* src = (const short8v*)(qb + (size_t)(qt_*64 + sr)*D_ + sc0);
    *(short8v*)&Qs[sr*TST + sc0]     = src[0];
    *(short8v*)&Qs[sr*TST + sc0 + 8] = src[1];
  }
  __syncthreads();
  short8v aQ0 = *(const short8v*)&Qs[(w*16+lr)*TST + lg*8];
  short8v aQ1 = *(const short8v*)&Qs[(w*16+lr)*TST + lg*8 + 32];

  float mreg[4], lreg[4];
  f32x4 accO[4] = {};
  #pragma unroll
  for(int r=0;r<4;r++){ mreg[r] = NEGBIG; lreg[r] = 0.f; }

  for(int kt=0; kt<=qt_; ++kt){
    __syncthreads();
    {
      const short8v* ksrc = (const short8v*)(kb + (size_t)(kt*64 + sr)*256 + sc0);
      *(short8v*)&Ks[sr*TST + sc0]     = ksrc[0];
      *(short8v*)&Ks[sr*TST + sc0 + 8] = ksrc[1];
      const short8v* vsrc = (const short8v*)(vb + (size_t)(kt*64 + sr)*256 + sc0);
      short8v v0 = vsrc[0], v1 = vsrc[1];
      #pragma unroll
      for(int i=0;i<8;i++){
        Vt[(sc0+i)*TST + vc]   = v0[i];
        Vt[(sc0+8+i)*TST + vc] = v1[i];
      }
    }
    __syncthreads();
    f32x4 s[4];
    #pragma unroll
    for(int fj=0; fj<4; fj++){
      short8v b0 = *(const short8v*)&Ks[(fj*16+lr)*TST + lg*8];
      short8v b1 = *(const short8v*)&Ks[(fj*16+lr)*TST + lg*8 + 32];
      f32x4 z = {};
      z = mfma16(aQ0, b0, z);
      z = mfma16(aQ1, b1, z);
      s[fj] = z;
    }
    #pragma unroll
    for(int fj=0; fj<4; fj++)
      #pragma unroll
      for(int r=0;r<4;r++){
        float v = s[fj][r]*0.125f;
        if(kt==qt_ && (fj*16+lr) > (w*16+lg*4+r)) v = NEGBIG;
        s[fj][r] = v;
      }
    float p[4][4], sc[4];
    #pragma unroll
    for(int r=0;r<4;r++){
      float mx = fmaxf(fmaxf(s[0][r],s[1][r]), fmaxf(s[2][r],s[3][r]));
      mx = fmaxf(mx, __shfl_xor(mx,1,64));
      mx = fmaxf(mx, __shfl_xor(mx,2,64));
      mx = fmaxf(mx, __shfl_xor(mx,4,64));
      mx = fmaxf(mx, __shfl_xor(mx,8,64));
      float mn = fmaxf(mreg[r], mx);
      sc[r] = __expf(mreg[r]-mn);
      float ps = 0.f;
      #pragma unroll
      for(int fj=0;fj<4;fj++){ float pv = __expf(s[fj][r]-mn); p[fj][r] = pv; ps += pv; }
      ps += __shfl_xor(ps,1,64); ps += __shfl_xor(ps,2,64);
      ps += __shfl_xor(ps,4,64); ps += __shfl_xor(ps,8,64);
      lreg[r] = lreg[r]*sc[r] + ps;
      mreg[r] = mn;
    }
    #pragma unroll
    for(int fj=0;fj<4;fj++)
      #pragma unroll
      for(int r=0;r<4;r++)
        accO[fj][r] *= sc[r];
    #pragma unroll
    for(int fj=0;fj<4;fj++)
      #pragma unroll
      for(int r=0;r<4;r++)
        Ps[w][(lg*4+r)*TST + fj*16+lr] = f2bs(p[fj][r]);
    // no barrier: Ps is per-wave, DS ops are in-order per wave
    short8v a0 = *(const short8v*)&Ps[w][lr*TST + lg*8];
    short8v a1 = *(const short8v*)&Ps[w][lr*TST + lg*8 + 32];
    #pragma unroll
    for(int fj=0;fj<4;fj++){
      int row = fj*16+lr;
      short8v b0 = *(const short8v*)&Vt[row*TST + ((lg^fj)<<3)];
      short8v b1 = *(const short8v*)&Vt[row*TST + (((lg^fj)+4)<<3)];
      accO[fj] = mfma16(a0, b0, accO[fj]);
      accO[fj] = mfma16(a1, b1, accO[fj]);
    }
  }
  #pragma unroll
  for(int r=0;r<4;r++){
    int qr = qt_*64 + w*16 + lg*4 + r;
    float inv = (lreg[r] > 0.f) ? 1.f/lreg[r] : 0.f;
    #pragma unroll
    for(int fj=0;fj<4;fj++)
      Out[((size_t)(b*S_+qr))*D_ + h*HD_ + fj*16+lr] = f2b(accO[fj][r]*inv);
  }
}

__global__ __launch_bounds__(64) void k_router(const float* __restrict__ X, const void* __restrict__ W,
                                               float* __restrict__ probs, float* __restrict__ p01,
                                               int* __restrict__ idx0buf, int* __restrict__ list,
                                               int* __restrict__ cnt, const int* __restrict__ flag){
  int isbf = flag[0];
  int t = blockIdx.x; int lane = threadIdx.x;
  float pe[8] = {};
  if(isbf){
    const bf16* Wb = (const bf16*)W;
    for(int d = lane; d < D_; d += 64){
      float xv = X[(size_t)t*D_ + d];
      #pragma unroll
      for(int e=0;e<8;e++) pe[e] += xv*b2f(Wb[(size_t)d*E_+e]);
    }
  } else {
    const float* Wf = (const float*)W;
    for(int d = lane; d < D_; d += 64){
      float xv = X[(size_t)t*D_ + d];
      #pragma unroll
      for(int e=0;e<8;e++) pe[e] += xv*Wf[(size_t)d*E_+e];
    }
  }
  for(int msk=1;msk<64;msk<<=1)
    #pragma unroll
    for(int e=0;e<8;e++) pe[e] += __shfl_xor(pe[e], msk, 64);
  if(lane == 0){
    float mx = pe[0];
    #pragma unroll
    for(int e=1;e<8;e++) mx = fmaxf(mx, pe[e]);
    float pr[8], sum = 0.f;
    #pragma unroll
    for(int e=0;e<8;e++){ pr[e] = __expf(pe[e]-mx); sum += pr[e]; }
    #pragma unroll
    for(int e=0;e<8;e++){ pr[e] /= sum; probs[t*8+e] = pr[e]; }
    int i0 = 0;
    #pragma unroll
    for(int e=1;e<8;e++) if(pe[e] > pe[i0]) i0 = e;
    int i1 = -1;
    #pragma unroll
    for(int e=0;e<8;e++){ if(e==i0) continue; if(i1<0 || pe[e] > pe[i1]) i1 = e; }
    p01[t*2]   = pr[i0];
    p01[t*2+1] = pr[i1];
    idx0buf[t] = i0;
    int pos = atomicAdd(&cnt[i0], 1);
    if(pos >= 0 && pos < NT_) list[i0*NT_ + pos] = t*2;
    pos     = atomicAdd(&cnt[i1], 1);
    if(pos >= 0 && pos < NT_) list[i1*NT_ + pos] = t*2 + 1;
  }
}

__global__ __launch_bounds__(256) void k_stats(const float* __restrict__ probs, const int* __restrict__ idx0buf,
                                               float* __restrict__ cnt0f, float* __restrict__ psum){
  int e = blockIdx.x; int tid = threadIdx.x;
  float sp = 0.f, sc = 0.f;
  for(int n = tid; n < NT_; n += 256){ sp += probs[n*8+e]; sc += (idx0buf[n]==e) ? 1.f : 0.f; }
  __shared__ float r1[256], r2[256];
  r1[tid] = sp; r2[tid] = sc; __syncthreads();
  for(int st=128; st>0; st>>=1){ if(tid<st){ r1[tid]+=r1[tid+st]; r2[tid]+=r2[tid+st]; } __syncthreads(); }
  if(tid==0){ psum[e] = r1[0]; cnt0f[e] = r2[0]; }
}

__global__ void k_finish(const float* __restrict__ cnt0f, const float* __restrict__ psum,
                         const int* __restrict__ cnt, int* __restrict__ offs,
                         bf16* __restrict__ auxb, float* __restrict__ auxf, const int* __restrict__ flag){
  if(threadIdx.x==0 && blockIdx.x==0){
    int o = 0;
    for(int e=0;e<8;e++){ offs[e] = o; int c = cnt[e]; if(c < 0) c = 0; if(c > NT_) c = NT_; o += c; }
    float aux = 0.f;
    for(int e=0;e<8;e++) aux += (cnt0f[e]*(1.f/(float)NT_))*(psum[e]*(1.f/(float)NT_));
    float v = aux*0.01f*8.f;
    if(flag[0]) auxb[0] = f2b(v); else auxf[0] = v;
  }
}

__global__ __launch_bounds__(256) void k_combine(const float* __restrict__ hbuf, const bf16* __restrict__ eosl,
                                                 const float* __restrict__ p01,
                                                 bf16* __restrict__ outb, float* __restrict__ outf,
                                                 const int* __restrict__ flag){
  int t = blockIdx.x; int tid = threadIdx.x;
  int isbf = flag[0];
  float p0 = p01[t*2], p1 = p01[t*2+1];
  #pragma unroll
  for(int i=0;i<4;i++){
    int d = tid + i*256;
    float v = hbuf[(size_t)t*D_ + d]
            + p0*b2f(eosl[((size_t)(t*2))*D_ + d])
            + p1*b2f(eosl[((size_t)(t*2+1))*D_ + d]);
    size_t o = (size_t)t*D_ + d;
    if(isbf) outb[o] = f2b(v); else outf[o] = v;
  }
}

static const size_t O_HBUF = 0;
static const size_t O_XN   = 0;
static const size_t O_QLIN = 16777216;
static const size_t O_KLIN = 33554432;
static const size_t O_VLIN = 37748736;
static const size_t O_AOUT = 41943040;
static const size_t O_XN2  = 16777216;
static const size_t O_T1E  = 33554432;
static const size_t O_T3E  = 44761088;
static const size_t O_HEXP = 55967744;
static const size_t O_T1S  = 33554432;
static const size_t O_T3S  = 39157760;
static const size_t O_SHH  = 44761088;
static const size_t O_EOSL = 16777216;
static const size_t O_PROBS= 67174400;
static const size_t O_P01  = 67305472;
static const size_t O_IDX0 = 67338240;
static const size_t O_LIST = 67354624;
static const size_t O_CNT  = 67485696;
static const size_t O_CNT0 = 67485728;
static const size_t O_PSUM = 67485760;
static const size_t O_OFFS = 67485792;
static const size_t O_FLAG = 67485824;

extern "C" void kernel_launch(void* const* d_in, const int* in_sizes, int n_in,
                              void* d_out, int out_size, void* d_ws, size_t ws_size,
                              hipStream_t stream){
  (void)in_sizes; (void)n_in; (void)out_size; (void)ws_size;
  char* ws = (char*)d_ws;
  float* xn   = (float*)(ws + O_XN);
  bf16* qlin  = (bf16*)(ws + O_QLIN);
  bf16* klin  = (bf16*)(ws + O_KLIN);
  bf16* vlin  = (bf16*)(ws + O_VLIN);
  bf16* aout  = (bf16*)(ws + O_AOUT);
  float* hbuf = (float*)(ws + O_HBUF);
  float* xn2  = (float*)(ws + O_XN2);
  bf16* t1e   = (bf16*)(ws + O_T1E);
  bf16* t3e   = (bf16*)(ws + O_T3E);
  bf16* hexp  = (bf16*)(ws + O_HEXP);
  bf16* t1s   = (bf16*)(ws + O_T1S);
  bf16* t3s   = (bf16*)(ws + O_T3S);
  bf16* shh   = (bf16*)(ws + O_SHH);
  bf16* eosl  = (bf16*)(ws + O_EOSL);
  float* probs=(float*)(ws + O_PROBS);
  float* p01 = (float*)(ws + O_P01);
  int*  idx0 = (int*)(ws + O_IDX0);
  int*  list = (int*)(ws + O_LIST);
  int*  cnt  = (int*)(ws + O_CNT);
  float* cnt0f=(float*)(ws + O_CNT0);
  float* psum= (float*)(ws + O_PSUM);
  int*  offs = (int*)(ws + O_OFFS);
  int*  flg  = (int*)(ws + O_FLAG);

  bf16* outb = (bf16*)d_out;
  float* outf = (float*)d_out;
  bf16* auxb = outb + (size_t)NT_*D_;
  float* auxf = outf + (size_t)NT_*D_;

  k_detect<<<1, 64, 0, stream>>>((const uint32_t*)d_in[14], flg, cnt);

  k_rms<<<NT_, 256, 0, stream>>>(d_in[0], d_in[14], xn, flg, 1);

  k_mgemm<float,0,4><<<dim3(8,32), 256, 0, stream>>>(xn, d_in[3], qlin, nullptr, NT_, D_, D_, D_, nullptr, nullptr, nullptr, flg);
  k_mgemm<float,0,4><<<dim3(2,32), 256, 0, stream>>>(xn, d_in[4], klin, nullptr, NT_, 256, D_, 256, nullptr, nullptr, nullptr, flg);
  k_mgemm<float,0,4><<<dim3(2,32), 256, 0, stream>>>(xn, d_in[5], vlin, nullptr, NT_, 256, D_, 256, nullptr, nullptr, nullptr, flg);

  k_rope<<<NT_, 256, 0, stream>>>(qlin, klin, d_in[1], d_in[2], flg);

  k_attn<<<dim3(S_/64, H_, B_), 256, 0, stream>>>(qlin, klin, vlin, aout);

  k_mgemm<bf16,0,1><<<dim3(8,32), 256, 0, stream>>>(aout, d_in[6], hbuf, d_in[0], NT_, D_, D_, D_, nullptr, nullptr, nullptr, flg);

  k_rms<<<NT_, 256, 0, stream>>>(hbuf, d_in[15], xn2, flg, 0);

  k_router<<<NT_, 64, 0, stream>>>(xn2, d_in[7], probs, p01, idx0, list, cnt, flg);
  k_stats<<<E_, 256, 0, stream>>>(probs, idx0, cnt0f, psum);
  k_finish<<<1, 64, 0, stream>>>(cnt0f, psum, cnt, offs, auxb, auxf, flg);

  k_mgemm<float,2,4><<<dim3(6,32,E_), 256, 0, stream>>>(xn2, d_in[8],  t1e, nullptr, 0, HIDDEN_, D_, HIDDEN_, cnt, offs, list, flg);
  k_mgemm<float,2,4><<<dim3(6,32,E_), 256, 0, stream>>>(xn2, d_in[10], t3e, nullptr, 0, HIDDEN_, D_, HIDDEN_, cnt, offs, list, flg);

  k_silu<<<(2*NT_*HIDDEN_/4 + 255)/256, 256, 0, stream>>>(t1e, t3e, hexp, 2*NT_*HIDDEN_/4);

  k_mgemm<float,0,4><<<dim3(6,32), 256, 0, stream>>>(xn2, d_in[11], t1s, nullptr, NT_, HIDDEN_, D_, HIDDEN_, nullptr, nullptr, nullptr, flg);
  k_mgemm<float,0,4><<<dim3(6,32), 256, 0, stream>>>(xn2, d_in[13], t3s, nullptr, NT_, HIDDEN_, D_, HIDDEN_, nullptr, nullptr, nullptr, flg);

  k_silu<<<(NT_*HIDDEN_/4 + 255)/256, 256, 0, stream>>>(t1s, t3s, shh, NT_*HIDDEN_/4);

  // expert ffn2: A rows contiguous at base+rloc (AMAP=0 in expert mode), scatter out via list
  k_mgemm<bf16,0,2><<<dim3(8,32,E_), 256, 0, stream>>>(hexp, d_in[9], eosl, nullptr, 0, D_, HIDDEN_, D_, cnt, offs, list, flg);
  // shared ffn2: hbuf += shh @ sw2
  k_mgemm<bf16,0,3><<<dim3(8,32), 256, 0, stream>>>(shh, d_in[12], hbuf, nullptr, NT_, D_, HIDDEN_, D_, nullptr, nullptr, nullptr, flg);

  k_combine<<<NT_, 256, 0, stream>>>(hbuf, eosl, p01, outb, outf, flg);
}

// Round 9
// 805.982 us; speedup vs baseline: 4.0949x; 1.3420x over previous
//
#include <hip/hip_runtime.h>
#include <hip/hip_bf16.h>
#include <cstdint>

#define B_ 2
#define S_ 2048
#define D_ 1024
#define H_ 16
#define HKV_ 4
#define HD_ 64
#define E_ 8
#define HIDDEN_ 684
#define NT_ (B_*S_)
#define NEGBIG (-1e30f)

using bf16 = __hip_bfloat16;
typedef __attribute__((ext_vector_type(8))) short short8v;
typedef __attribute__((ext_vector_type(4))) short short4v;
typedef __attribute__((ext_vector_type(4))) float f32x4;

static __device__ __forceinline__ float b2f(bf16 v){ return __bfloat162float(v); }
static __device__ __forceinline__ bf16 f2b(float v){ return __float2bfloat16(v); }
static __device__ __forceinline__ short f2bs(float v){ bf16 h = f2b(v); return *reinterpret_cast<short*>(&h); }
static __device__ __forceinline__ float dload(const void* p, size_t i, int isbf){
  return isbf ? b2f(((const bf16*)p)[i]) : ((const float*)p)[i];
}

__global__ void k_detect(const uint32_t* __restrict__ g, int* __restrict__ flag, int* __restrict__ cnt){
  if(threadIdx.x == 0 && blockIdx.x == 0){
    uint32_t w0 = g[0], w1 = g[1], w2 = g[2], w3 = g[3];
    int bf;
    if(w0==0x3F803F80u && w1==0x3F803F80u && w2==0x3F803F80u && w3==0x3F803F80u) bf = 1;
    else if(w0==0x3F800000u && w1==0x3F800000u && w2==0x3F800000u && w3==0x3F800000u) bf = 0;
    else bf = 1;
    flag[0] = bf;
  }
  if(threadIdx.x < E_ && blockIdx.x == 0) cnt[threadIdx.x] = 0;
}

// ---------------- RMSNorm -> bf16 out (+ optional f32 copy for router) ----------------
__global__ __launch_bounds__(256) void k_rms(const void* __restrict__ X, const void* __restrict__ g,
                                             bf16* __restrict__ outb, float* __restrict__ outf,
                                             const int* __restrict__ flag, int xdyn){
  int isbf = flag[0]; int xb = xdyn ? isbf : 0;
  int t = blockIdx.x; int tid = threadIdx.x;
  float v[4]; float ss = 0.f;
  #pragma unroll
  for(int i=0;i<4;i++){ v[i] = dload(X, (size_t)t*D_ + tid + i*256, xb); ss += v[i]*v[i]; }
  __shared__ float red[256];
  red[tid] = ss; __syncthreads();
  for(int st=128; st>0; st>>=1){ if(tid<st) red[tid] += red[tid+st]; __syncthreads(); }
  float r = rsqrtf(red[0]*(1.f/(float)D_) + 1e-5f);
  #pragma unroll
  for(int i=0;i<4;i++){
    int d = tid + i*256;
    float val = v[i]*r*dload(g, d, isbf);
    outb[(size_t)t*D_ + d] = f2b(val);
    if(outf) outf[(size_t)t*D_ + d] = val;
  }
}

// =====================================================================
// MFMA GEMM, BM=128 BN=64 BK=32, 4 waves (wave = 32 rows x 64 cols, 2x4 frags),
// double-buffered LDS + register prefetch, ONE barrier per K-step.
// A always bf16. B runtime-dtype. XOR k-block swizzle (verified r6-r8).
// AMAP: 0 = base+rloc, 2 = gather list>>1
// OMODE: 1 f32+resid, 2 bf16 scatter via list, 3 f32 accumulate, 4 bf16 store
// =====================================================================
#define ASTRIDE 40

static __device__ __forceinline__ f32x4 mfma16(short8v a, short8v b, f32x4 c){
  return __builtin_amdgcn_mfma_f32_16x16x32_bf16(a, b, c, 0, 0, 0);
}

template<int AMAP, int OMODE>
__global__ __launch_bounds__(256) void k_mgemm(
    const bf16* __restrict__ A, const void* __restrict__ Bw, void* __restrict__ Cout,
    const void* __restrict__ resid,
    int M, int N, int K, int ldc,
    const int* __restrict__ cnt, const int* __restrict__ offs, const int* __restrict__ list,
    const int* __restrict__ flag)
{
  int isbf = flag[0];
  int e = blockIdx.z;
  int base = 0; size_t eoff = 0;
  if(cnt){
    M = cnt[e]; if(M<0) M=0; if(M>NT_) M=NT_;
    base = offs[e];
    eoff = (size_t)e*(size_t)K*(size_t)N;
  }
  int m0 = blockIdx.y*128; if(m0 >= M) return;
  int n0 = blockIdx.x*64;

  __shared__ short As[2][128*ASTRIDE];
  __shared__ short Bs[2][64*ASTRIDE];
  __shared__ int rowA[128];

  int tid = threadIdx.x;
  int w = tid>>6, l = tid&63, lr = l&15, lg = l>>4;

  if(tid < 128){
    int rloc = m0 + tid;
    int ar = -1;
    if(rloc < M) ar = (AMAP==2) ? (list[e*NT_ + rloc]>>1) : (base + rloc);
    rowA[tid] = ar;
  }
  __syncthreads();

  int srow = tid>>1, skh = (tid&1)*16;
  int keya = (srow>>4)&3, kb0 = skh>>3;
  int bk = tid>>3, bnc = (tid&7)*8;
  int keyb = ((tid&7)>>1)&3;
  int bcol = (((bk>>3)^keyb)<<3) + (bk&7);
  int arow = rowA[srow];

  short8v rA0, rA1, rB;

  auto loadAB = [&](int kt){
    int k0 = kt*32;
    { // A (bf16)
      short tmp[16];
      if(arow >= 0 && k0+skh+16 <= K){
        const short4v* src = (const short4v*)(A + (size_t)arow*K + k0 + skh);
        #pragma unroll
        for(int c=0;c<4;c++) *(short4v*)&tmp[c*4] = src[c];
      } else {
        #pragma unroll
        for(int i=0;i<16;i++){
          int gk = k0+skh+i;
          short v = 0;
          if(arow>=0 && gk<K) v = *(const short*)&A[(size_t)arow*K+gk];
          tmp[i] = v;
        }
      }
      #pragma unroll
      for(int i=0;i<8;i++){ rA0[i]=tmp[i]; rA1[i]=tmp[8+i]; }
    }
    { // B (runtime dtype)
      int gk = k0 + bk;
      short tmp[8];
      if(gk < K && n0+bnc+8 <= N){
        size_t bb = eoff + (size_t)gk*N + n0 + bnc;
        if(isbf){
          const short4v* src = (const short4v*)((const bf16*)Bw + bb);
          *(short4v*)&tmp[0] = src[0];
          *(short4v*)&tmp[4] = src[1];
        } else {
          const f32x4* src = (const f32x4*)((const float*)Bw + bb);
          f32x4 f0 = src[0], f1 = src[1];
          #pragma unroll
          for(int i=0;i<4;i++){ tmp[i]=f2bs(f0[i]); tmp[4+i]=f2bs(f1[i]); }
        }
      } else {
        #pragma unroll
        for(int i=0;i<8;i++){
          int gn = n0+bnc+i;
          float v = 0.f;
          if(gk<K && gn<N) v = dload(Bw, eoff + (size_t)gk*N + gn, isbf);
          tmp[i] = f2bs(v);
        }
      }
      #pragma unroll
      for(int i=0;i<8;i++) rB[i]=tmp[i];
    }
  };
  auto writeAB = [&](int buf){
    *(short8v*)&As[buf][srow*ASTRIDE + ((kb0^keya)<<3)]     = rA0;
    *(short8v*)&As[buf][srow*ASTRIDE + (((kb0+1)^keya)<<3)] = rA1;
    #pragma unroll
    for(int i=0;i<8;i++) Bs[buf][(bnc+i)*ASTRIDE + bcol] = rB[i];
  };

  f32x4 acc[2][4] = {};
  int KT = (K+31)>>5;

  loadAB(0); writeAB(0);
  __syncthreads();
  int cur = 0;
  for(int kt=0; kt<KT; ++kt){
    bool more = (kt+1 < KT);
    if(more) loadAB(kt+1);          // global loads issue; consumed after MFMA
    short8v a[2], b[4];
    #pragma unroll
    for(int fi=0;fi<2;fi++)
      a[fi] = *(const short8v*)&As[cur][(w*32+fi*16+lr)*ASTRIDE + ((lg^((w*2+fi)&3))<<3)];
    #pragma unroll
    for(int fj=0;fj<4;fj++)
      b[fj] = *(const short8v*)&Bs[cur][(fj*16+lr)*ASTRIDE + ((lg^fj)<<3)];
    #pragma unroll
    for(int fi=0;fi<2;fi++)
      #pragma unroll
      for(int fj=0;fj<4;fj++)
        acc[fi][fj] = mfma16(a[fi], b[fj], acc[fi][fj]);
    if(more){ writeAB(cur^1); cur ^= 1; }
    __syncthreads();                // single barrier per step
  }

  #pragma unroll
  for(int fi=0;fi<2;fi++){
    #pragma unroll
    for(int r=0;r<4;r++){
      int rl = m0 + w*32 + fi*16 + lg*4 + r;
      if(rl >= M) continue;
      int orow;
      if(OMODE==2){ orow = list[e*NT_ + rl]; if(orow<0||orow>=2*NT_) continue; }
      else orow = base + rl;
      #pragma unroll
      for(int fj=0;fj<4;fj++){
        int gcol = n0 + fj*16 + lr;
        if(gcol >= N) continue;
        float v = acc[fi][fj][r];
        size_t o = (size_t)orow*ldc + gcol;
        if(OMODE==1)      ((float*)Cout)[o] = v + dload(resid, o, isbf);
        else if(OMODE==2) ((bf16*)Cout)[o] = f2b(v);
        else if(OMODE==3) ((float*)Cout)[o] = ((float*)Cout)[o] + v;
        else              ((bf16*)Cout)[o] = f2b(v);
      }
    }
  }
}

// =====================================================================
// Fused FFN1: out[base+r] = silu(A@W1) * (A@W3), same geometry/pipeline.
// =====================================================================
template<int AMAP>
__global__ __launch_bounds__(256) void k_ffn1f(
    const bf16* __restrict__ A, const void* __restrict__ W1, const void* __restrict__ W3,
    bf16* __restrict__ Out, int M, int N, int K,
    const int* __restrict__ cnt, const int* __restrict__ offs, const int* __restrict__ list,
    const int* __restrict__ flag)
{
  int isbf = flag[0];
  int e = blockIdx.z;
  int base = 0; size_t eoff = 0;
  if(cnt){
    M = cnt[e]; if(M<0) M=0; if(M>NT_) M=NT_;
    base = offs[e];
    eoff = (size_t)e*(size_t)K*(size_t)N;
  }
  int m0 = blockIdx.y*128; if(m0 >= M) return;
  int n0 = blockIdx.x*64;

  __shared__ short As[2][128*ASTRIDE];
  __shared__ short B1s[2][64*ASTRIDE];
  __shared__ short B3s[2][64*ASTRIDE];
  __shared__ int rowA[128];

  int tid = threadIdx.x;
  int w = tid>>6, l = tid&63, lr = l&15, lg = l>>4;

  if(tid < 128){
    int rloc = m0 + tid;
    int ar = -1;
    if(rloc < M) ar = (AMAP==2) ? (list[e*NT_ + rloc]>>1) : (base + rloc);
    rowA[tid] = ar;
  }
  __syncthreads();

  int srow = tid>>1, skh = (tid&1)*16;
  int keya = (srow>>4)&3, kb0 = skh>>3;
  int bk = tid>>3, bnc = (tid&7)*8;
  int keyb = ((tid&7)>>1)&3;
  int bcol = (((bk>>3)^keyb)<<3) + (bk&7);
  int arow = rowA[srow];

  short8v rA0, rA1, rB1, rB3;

  auto loadB = [&](const void* Bw, int kt, short8v& rB){
    int k0 = kt*32;
    int gk = k0 + bk;
    short tmp[8];
    if(gk < K && n0+bnc+8 <= N){
      size_t bb = eoff + (size_t)gk*N + n0 + bnc;
      if(isbf){
        const short4v* src = (const short4v*)((const bf16*)Bw + bb);
        *(short4v*)&tmp[0] = src[0];
        *(short4v*)&tmp[4] = src[1];
      } else {
        const f32x4* src = (const f32x4*)((const float*)Bw + bb);
        f32x4 f0 = src[0], f1 = src[1];
        #pragma unroll
        for(int i=0;i<4;i++){ tmp[i]=f2bs(f0[i]); tmp[4+i]=f2bs(f1[i]); }
      }
    } else {
      #pragma unroll
      for(int i=0;i<8;i++){
        int gn = n0+bnc+i;
        float v = 0.f;
        if(gk<K && gn<N) v = dload(Bw, eoff + (size_t)gk*N + gn, isbf);
        tmp[i] = f2bs(v);
      }
    }
    #pragma unroll
    for(int i=0;i<8;i++) rB[i]=tmp[i];
  };
  auto loadA = [&](int kt){
    int k0 = kt*32;
    short tmp[16];
    if(arow >= 0 && k0+skh+16 <= K){
      const short4v* src = (const short4v*)(A + (size_t)arow*K + k0 + skh);
      #pragma unroll
      for(int c=0;c<4;c++) *(short4v*)&tmp[c*4] = src[c];
    } else {
      #pragma unroll
      for(int i=0;i<16;i++){
        int gk = k0+skh+i;
        short v = 0;
        if(arow>=0 && gk<K) v = *(const short*)&A[(size_t)arow*K+gk];
        tmp[i] = v;
      }
    }
    #pragma unroll
    for(int i=0;i<8;i++){ rA0[i]=tmp[i]; rA1[i]=tmp[8+i]; }
  };
  auto writeAll = [&](int buf){
    *(short8v*)&As[buf][srow*ASTRIDE + ((kb0^keya)<<3)]     = rA0;
    *(short8v*)&As[buf][srow*ASTRIDE + (((kb0+1)^keya)<<3)] = rA1;
    #pragma unroll
    for(int i=0;i<8;i++){
      B1s[buf][(bnc+i)*ASTRIDE + bcol] = rB1[i];
      B3s[buf][(bnc+i)*ASTRIDE + bcol] = rB3[i];
    }
  };

  f32x4 a1[2][4] = {}, a3[2][4] = {};
  int KT = (K+31)>>5;

  loadA(0); loadB(W1, 0, rB1); loadB(W3, 0, rB3); writeAll(0);
  __syncthreads();
  int cur = 0;
  for(int kt=0; kt<KT; ++kt){
    bool more = (kt+1 < KT);
    if(more){ loadA(kt+1); loadB(W1, kt+1, rB1); loadB(W3, kt+1, rB3); }
    short8v a[2], b1[4], b3[4];
    #pragma unroll
    for(int fi=0;fi<2;fi++)
      a[fi] = *(const short8v*)&As[cur][(w*32+fi*16+lr)*ASTRIDE + ((lg^((w*2+fi)&3))<<3)];
    #pragma unroll
    for(int fj=0;fj<4;fj++){
      b1[fj] = *(const short8v*)&B1s[cur][(fj*16+lr)*ASTRIDE + ((lg^fj)<<3)];
      b3[fj] = *(const short8v*)&B3s[cur][(fj*16+lr)*ASTRIDE + ((lg^fj)<<3)];
    }
    #pragma unroll
    for(int fi=0;fi<2;fi++)
      #pragma unroll
      for(int fj=0;fj<4;fj++){
        a1[fi][fj] = mfma16(a[fi], b1[fj], a1[fi][fj]);
        a3[fi][fj] = mfma16(a[fi], b3[fj], a3[fi][fj]);
      }
    if(more){ writeAll(cur^1); cur ^= 1; }
    __syncthreads();
  }

  #pragma unroll
  for(int fi=0;fi<2;fi++){
    #pragma unroll
    for(int r=0;r<4;r++){
      int rl = m0 + w*32 + fi*16 + lg*4 + r;
      if(rl >= M) continue;
      int orow = base + rl;
      #pragma unroll
      for(int fj=0;fj<4;fj++){
        int gcol = n0 + fj*16 + lr;
        if(gcol >= N) continue;
        float sg = a1[fi][fj][r];
        float v = (sg/(1.f+__expf(-sg))) * a3[fi][fj][r];
        Out[(size_t)orow*N + gcol] = f2b(v);
      }
    }
  }
}

// ---------------- RoPE in-place on bf16 q and k ----------------
__global__ __launch_bounds__(256) void k_rope(bf16* __restrict__ ql, bf16* __restrict__ kl,
                                              const void* __restrict__ fc, const void* __restrict__ fs,
                                              const int* __restrict__ flag){
  int isbf = flag[0];
  int t = blockIdx.x; int s = t % S_;
  int tid = threadIdx.x;
  for(int p0 = tid; p0 < 512; p0 += 256){
    int h = p0>>5, p = p0&31;
    float c = dload(fc, s*32+p, isbf), sn = dload(fs, s*32+p, isbf);
    size_t o = (size_t)t*D_ + h*64 + 2*p;
    float xr = b2f(ql[o]), xi = b2f(ql[o+1]);
    ql[o]   = f2b(xr*c - xi*sn);
    ql[o+1] = f2b(xr*sn + xi*c);
  }
  if(tid < 128){
    int h = tid>>5, p = tid&31;
    float c = dload(fc, s*32+p, isbf), sn = dload(fs, s*32+p, isbf);
    size_t o = (size_t)t*256 + h*64 + 2*p;
    float xr = b2f(kl[o]), xi = b2f(kl[o+1]);
    kl[o]   = f2b(xr*c - xi*sn);
    kl[o+1] = f2b(xr*sn + xi*c);
  }
}

#define TST 72

__global__ __launch_bounds__(256) void k_attn(const bf16* __restrict__ Q, const bf16* __restrict__ Kg,
                                              const bf16* __restrict__ V, bf16* __restrict__ Out){
  int qt_ = (S_/64 - 1) - blockIdx.x;
  int h = blockIdx.y, b = blockIdx.z;
  int kvh = h>>2;
  const bf16* qb = Q + (size_t)b*S_*D_ + h*HD_;
  const bf16* kb = Kg + (size_t)b*S_*256 + kvh*HD_;
  const bf16* vb = V  + (size_t)b*S_*256 + kvh*HD_;
  __shared__ short Qs[64*TST];
  __shared__ short Ks[64*TST];
  __shared__ short Vt[64*TST];
  __shared__ short Ps[4][16*TST];
  int tid = threadIdx.x;
  int w = tid>>6, l = tid&63, lr = l&15, lg = l>>4;
  int sr = tid>>2, sc0 = (tid&3)*16;
  int vc = (((sr>>3)^(tid&3))<<3) + (sr&7);

  {
    const short8v* src = (const short8v*)(qb + (size_t)(qt_*64 + sr)*D_ + sc0);
    *(short8v*)&Qs[sr*TST + sc0]     = src[0];
    *(short8v*)&Qs[sr*TST + sc0 + 8] = src[1];
  }
  __syncthreads();
  short8v aQ0 = *(const short8v*)&Qs[(w*16+lr)*TST + lg*8];
  short8v aQ1 = *(const short8v*)&Qs[(w*16+lr)*TST + lg*8 + 32];

  float mreg[4], lreg[4];
  f32x4 accO[4] = {};
  #pragma unroll
  for(int r=0;r<4;r++){ mreg[r] = NEGBIG; lreg[r] = 0.f; }

  for(int kt=0; kt<=qt_; ++kt){
    __syncthreads();
    {
      const short8v* ksrc = (const short8v*)(kb + (size_t)(kt*64 + sr)*256 + sc0);
      *(short8v*)&Ks[sr*TST + sc0]     = ksrc[0];
      *(short8v*)&Ks[sr*TST + sc0 + 8] = ksrc[1];
      const short8v* vsrc = (const short8v*)(vb + (size_t)(kt*64 + sr)*256 + sc0);
      short8v v0 = vsrc[0], v1 = vsrc[1];
      #pragma unroll
      for(int i=0;i<8;i++){
        Vt[(sc0+i)*TST + vc]   = v0[i];
        Vt[(sc0+8+i)*TST + vc] = v1[i];
      }
    }
    __syncthreads();
    f32x4 s[4];
    #pragma unroll
    for(int fj=0; fj<4; fj++){
      short8v b0 = *(const short8v*)&Ks[(fj*16+lr)*TST + lg*8];
      short8v b1 = *(const short8v*)&Ks[(fj*16+lr)*TST + lg*8 + 32];
      f32x4 z = {};
      z = mfma16(aQ0, b0, z);
      z = mfma16(aQ1, b1, z);
      s[fj] = z;
    }
    #pragma unroll
    for(int fj=0; fj<4; fj++)
      #pragma unroll
      for(int r=0;r<4;r++){
        float v = s[fj][r]*0.125f;
        if(kt==qt_ && (fj*16+lr) > (w*16+lg*4+r)) v = NEGBIG;
        s[fj][r] = v;
      }
    float p[4][4], sc[4];
    #pragma unroll
    for(int r=0;r<4;r++){
      float mx = fmaxf(fmaxf(s[0][r],s[1][r]), fmaxf(s[2][r],s[3][r]));
      mx = fmaxf(mx, __shfl_xor(mx,1,64));
      mx = fmaxf(mx, __shfl_xor(mx,2,64));
      mx = fmaxf(mx, __shfl_xor(mx,4,64));
      mx = fmaxf(mx, __shfl_xor(mx,8,64));
      float mn = fmaxf(mreg[r], mx);
      sc[r] = __expf(mreg[r]-mn);
      float ps = 0.f;
      #pragma unroll
      for(int fj=0;fj<4;fj++){ float pv = __expf(s[fj][r]-mn); p[fj][r] = pv; ps += pv; }
      ps += __shfl_xor(ps,1,64); ps += __shfl_xor(ps,2,64);
      ps += __shfl_xor(ps,4,64); ps += __shfl_xor(ps,8,64);
      lreg[r] = lreg[r]*sc[r] + ps;
      mreg[r] = mn;
    }
    #pragma unroll
    for(int fj=0;fj<4;fj++)
      #pragma unroll
      for(int r=0;r<4;r++)
        accO[fj][r] *= sc[r];
    #pragma unroll
    for(int fj=0;fj<4;fj++)
      #pragma unroll
      for(int r=0;r<4;r++)
        Ps[w][(lg*4+r)*TST + fj*16+lr] = f2bs(p[fj][r]);
    short8v a0 = *(const short8v*)&Ps[w][lr*TST + lg*8];
    short8v a1 = *(const short8v*)&Ps[w][lr*TST + lg*8 + 32];
    #pragma unroll
    for(int fj=0;fj<4;fj++){
      int row = fj*16+lr;
      short8v b0 = *(const short8v*)&Vt[row*TST + ((lg^fj)<<3)];
      short8v b1 = *(const short8v*)&Vt[row*TST + (((lg^fj)+4)<<3)];
      accO[fj] = mfma16(a0, b0, accO[fj]);
      accO[fj] = mfma16(a1, b1, accO[fj]);
    }
  }
  #pragma unroll
  for(int r=0;r<4;r++){
    int qr = qt_*64 + w*16 + lg*4 + r;
    float inv = (lreg[r] > 0.f) ? 1.f/lreg[r] : 0.f;
    #pragma unroll
    for(int fj=0;fj<4;fj++)
      Out[((size_t)(b*S_+qr))*D_ + h*HD_ + fj*16+lr] = f2b(accO[fj][r]*inv);
  }
}

__global__ __launch_bounds__(64) void k_router(const float* __restrict__ X, const void* __restrict__ W,
                                               float* __restrict__ probs, float* __restrict__ p01,
                                               int* __restrict__ idx0buf, int* __restrict__ list,
                                               int* __restrict__ cnt, const int* __restrict__ flag){
  int isbf = flag[0];
  int t = blockIdx.x; int lane = threadIdx.x;
  float pe[8] = {};
  if(isbf){
    const bf16* Wb = (const bf16*)W;
    for(int d = lane; d < D_; d += 64){
      float xv = X[(size_t)t*D_ + d];
      #pragma unroll
      for(int e=0;e<8;e++) pe[e] += xv*b2f(Wb[(size_t)d*E_+e]);
    }
  } else {
    const float* Wf = (const float*)W;
    for(int d = lane; d < D_; d += 64){
      float xv = X[(size_t)t*D_ + d];
      #pragma unroll
      for(int e=0;e<8;e++) pe[e] += xv*Wf[(size_t)d*E_+e];
    }
  }
  for(int msk=1;msk<64;msk<<=1)
    #pragma unroll
    for(int e=0;e<8;e++) pe[e] += __shfl_xor(pe[e], msk, 64);
  if(lane == 0){
    float mx = pe[0];
    #pragma unroll
    for(int e=1;e<8;e++) mx = fmaxf(mx, pe[e]);
    float pr[8], sum = 0.f;
    #pragma unroll
    for(int e=0;e<8;e++){ pr[e] = __expf(pe[e]-mx); sum += pr[e]; }
    #pragma unroll
    for(int e=0;e<8;e++){ pr[e] /= sum; probs[t*8+e] = pr[e]; }
    int i0 = 0;
    #pragma unroll
    for(int e=1;e<8;e++) if(pe[e] > pe[i0]) i0 = e;
    int i1 = -1;
    #pragma unroll
    for(int e=0;e<8;e++){ if(e==i0) continue; if(i1<0 || pe[e] > pe[i1]) i1 = e; }
    p01[t*2]   = pr[i0];
    p01[t*2+1] = pr[i1];
    idx0buf[t] = i0;
    int pos = atomicAdd(&cnt[i0], 1);
    if(pos >= 0 && pos < NT_) list[i0*NT_ + pos] = t*2;
    pos     = atomicAdd(&cnt[i1], 1);
    if(pos >= 0 && pos < NT_) list[i1*NT_ + pos] = t*2 + 1;
  }
}

__global__ __launch_bounds__(256) void k_stats(const float* __restrict__ probs, const int* __restrict__ idx0buf,
                                               float* __restrict__ cnt0f, float* __restrict__ psum){
  int e = blockIdx.x; int tid = threadIdx.x;
  float sp = 0.f, sc = 0.f;
  for(int n = tid; n < NT_; n += 256){ sp += probs[n*8+e]; sc += (idx0buf[n]==e) ? 1.f : 0.f; }
  __shared__ float r1[256], r2[256];
  r1[tid] = sp; r2[tid] = sc; __syncthreads();
  for(int st=128; st>0; st>>=1){ if(tid<st){ r1[tid]+=r1[tid+st]; r2[tid]+=r2[tid+st]; } __syncthreads(); }
  if(tid==0){ psum[e] = r1[0]; cnt0f[e] = r2[0]; }
}

__global__ void k_finish(const float* __restrict__ cnt0f, const float* __restrict__ psum,
                         const int* __restrict__ cnt, int* __restrict__ offs,
                         bf16* __restrict__ auxb, float* __restrict__ auxf, const int* __restrict__ flag){
  if(threadIdx.x==0 && blockIdx.x==0){
    int o = 0;
    for(int e=0;e<8;e++){ offs[e] = o; int c = cnt[e]; if(c < 0) c = 0; if(c > NT_) c = NT_; o += c; }
    float aux = 0.f;
    for(int e=0;e<8;e++) aux += (cnt0f[e]*(1.f/(float)NT_))*(psum[e]*(1.f/(float)NT_));
    float v = aux*0.01f*8.f;
    if(flag[0]) auxb[0] = f2b(v); else auxf[0] = v;
  }
}

__global__ __launch_bounds__(256) void k_combine(const float* __restrict__ hbuf, const bf16* __restrict__ eosl,
                                                 const float* __restrict__ p01,
                                                 bf16* __restrict__ outb, float* __restrict__ outf,
                                                 const int* __restrict__ flag){
  int t = blockIdx.x; int tid = threadIdx.x;
  int isbf = flag[0];
  float p0 = p01[t*2], p1 = p01[t*2+1];
  #pragma unroll
  for(int i=0;i<4;i++){
    int d = tid + i*256;
    float v = hbuf[(size_t)t*D_ + d]
            + p0*b2f(eosl[((size_t)(t*2))*D_ + d])
            + p1*b2f(eosl[((size_t)(t*2+1))*D_ + d]);
    size_t o = (size_t)t*D_ + d;
    if(isbf) outb[o] = f2b(v); else outf[o] = v;
  }
}

// ---------------- workspace (bytes), peak ~63.3 MB (< 67.45 proven) ----------------
static const size_t O_HBUF = 0;          // f32 4096x1024 [0,16777216)
static const size_t O_XNB  = 16777216;   // bf16 4096x1024 -> 25165824 (dead after QKV)
static const size_t O_QLIN = 25165824;   // bf16 -> 33554432
static const size_t O_KLIN = 33554432;   // bf16 -> 35651584
static const size_t O_VLIN = 35651584;   // bf16 -> 37748736
static const size_t O_AOUT = 37748736;   // bf16 -> 46137344 (dead after wo)
static const size_t O_XN2B = 16777216;   // bf16 (over XNB) -> 25165824
static const size_t O_XN2F = 25165824;   // f32 (over QLIN/KLIN/VLIN/AOUT-head) -> 41943040
static const size_t O_HEXP = 46137344;   // bf16 8192x684 -> 57344000
static const size_t O_SHH  = 57344000;   // bf16 4096x684 -> 62947328
static const size_t O_EOSL = 16777216;   // bf16 8192x1024 (over XN2B+XN2F-head, dead) -> 33554432
static const size_t O_PROBS= 62947328;   // -> 63078400
static const size_t O_P01  = 63078400;   // -> 63111168
static const size_t O_IDX0 = 63111168;   // -> 63127552
static const size_t O_LIST = 63127552;   // -> 63258624
static const size_t O_CNT  = 63258624;
static const size_t O_CNT0 = 63258656;
static const size_t O_PSUM = 63258688;
static const size_t O_OFFS = 63258720;
static const size_t O_FLAG = 63258752;

extern "C" void kernel_launch(void* const* d_in, const int* in_sizes, int n_in,
                              void* d_out, int out_size, void* d_ws, size_t ws_size,
                              hipStream_t stream){
  (void)in_sizes; (void)n_in; (void)out_size; (void)ws_size;
  char* ws = (char*)d_ws;
  float* hbuf = (float*)(ws + O_HBUF);
  bf16* xnb   = (bf16*)(ws + O_XNB);
  bf16* qlin  = (bf16*)(ws + O_QLIN);
  bf16* klin  = (bf16*)(ws + O_KLIN);
  bf16* vlin  = (bf16*)(ws + O_VLIN);
  bf16* aout  = (bf16*)(ws + O_AOUT);
  bf16* xn2b  = (bf16*)(ws + O_XN2B);
  float* xn2f = (float*)(ws + O_XN2F);
  bf16* hexp  = (bf16*)(ws + O_HEXP);
  bf16* shh   = (bf16*)(ws + O_SHH);
  bf16* eosl  = (bf16*)(ws + O_EOSL);
  float* probs=(float*)(ws + O_PROBS);
  float* p01 = (float*)(ws + O_P01);
  int*  idx0 = (int*)(ws + O_IDX0);
  int*  list = (int*)(ws + O_LIST);
  int*  cnt  = (int*)(ws + O_CNT);
  float* cnt0f=(float*)(ws + O_CNT0);
  float* psum= (float*)(ws + O_PSUM);
  int*  offs = (int*)(ws + O_OFFS);
  int*  flg  = (int*)(ws + O_FLAG);

  bf16* outb = (bf16*)d_out;
  float* outf = (float*)d_out;
  bf16* auxb = outb + (size_t)NT_*D_;
  float* auxf = outf + (size_t)NT_*D_;

  k_detect<<<1, 64, 0, stream>>>((const uint32_t*)d_in[14], flg, cnt);

  // ---- attention block ----
  k_rms<<<NT_, 256, 0, stream>>>(d_in[0], d_in[14], xnb, nullptr, flg, 1);

  k_mgemm<0,4><<<dim3(16,32), 256, 0, stream>>>(xnb, d_in[3], qlin, nullptr, NT_, D_, D_, D_, nullptr, nullptr, nullptr, flg);
  k_mgemm<0,4><<<dim3(4,32),  256, 0, stream>>>(xnb, d_in[4], klin, nullptr, NT_, 256, D_, 256, nullptr, nullptr, nullptr, flg);
  k_mgemm<0,4><<<dim3(4,32),  256, 0, stream>>>(xnb, d_in[5], vlin, nullptr, NT_, 256, D_, 256, nullptr, nullptr, nullptr, flg);

  k_rope<<<NT_, 256, 0, stream>>>(qlin, klin, d_in[1], d_in[2], flg);

  k_attn<<<dim3(S_/64, H_, B_), 256, 0, stream>>>(qlin, klin, vlin, aout);

  k_mgemm<0,1><<<dim3(16,32), 256, 0, stream>>>(aout, d_in[6], hbuf, d_in[0], NT_, D_, D_, D_, nullptr, nullptr, nullptr, flg);

  // ---- MoE block ----
  k_rms<<<NT_, 256, 0, stream>>>(hbuf, d_in[15], xn2b, xn2f, flg, 0);

  k_router<<<NT_, 64, 0, stream>>>(xn2f, d_in[7], probs, p01, idx0, list, cnt, flg);
  k_stats<<<E_, 256, 0, stream>>>(probs, idx0, cnt0f, psum);
  k_finish<<<1, 64, 0, stream>>>(cnt0f, psum, cnt, offs, auxb, auxf, flg);

  // fused ffn1 (+silu): expert (gather) and shared (dense)
  k_ffn1f<2><<<dim3(11,32,E_), 256, 0, stream>>>(xn2b, d_in[8], d_in[10], hexp, 0, HIDDEN_, D_, cnt, offs, list, flg);
  k_ffn1f<0><<<dim3(11,32),    256, 0, stream>>>(xn2b, d_in[11], d_in[13], shh, NT_, HIDDEN_, D_, nullptr, nullptr, nullptr, flg);

  // ffn2: expert scatter, shared accumulate into hbuf
  k_mgemm<0,2><<<dim3(16,32,E_), 256, 0, stream>>>(hexp, d_in[9], eosl, nullptr, 0, D_, HIDDEN_, D_, cnt, offs, list, flg);
  k_mgemm<0,3><<<dim3(16,32),    256, 0, stream>>>(shh, d_in[12], hbuf, nullptr, NT_, D_, HIDDEN_, D_, nullptr, nullptr, nullptr, flg);

  k_combine<<<NT_, 256, 0, stream>>>(hbuf, eosl, p01, outb, outf, flg);
}

// Round 10
// 782.345 us; speedup vs baseline: 4.2186x; 1.0302x over previous
//
#include <hip/hip_runtime.h>
#include <hip/hip_bf16.h>
#include <cstdint>

#define B_ 2
#define S_ 2048
#define D_ 1024
#define H_ 16
#define HKV_ 4
#define HD_ 64
#define E_ 8
#define HIDDEN_ 684
#define NT_ (B_*S_)
#define NEGBIG (-1e30f)

using bf16 = __hip_bfloat16;
typedef __attribute__((ext_vector_type(8))) short short8v;
typedef __attribute__((ext_vector_type(4))) short short4v;
typedef __attribute__((ext_vector_type(4))) float f32x4;

static __device__ __forceinline__ float b2f(bf16 v){ return __bfloat162float(v); }
static __device__ __forceinline__ bf16 f2b(float v){ return __float2bfloat16(v); }
static __device__ __forceinline__ short f2bs(float v){ bf16 h = f2b(v); return *reinterpret_cast<short*>(&h); }
static __device__ __forceinline__ float dload(const void* p, size_t i, int isbf){
  return isbf ? b2f(((const bf16*)p)[i]) : ((const float*)p)[i];
}

__global__ void k_detect(const uint32_t* __restrict__ g, int* __restrict__ flag, int* __restrict__ cnt){
  if(threadIdx.x == 0 && blockIdx.x == 0){
    uint32_t w0 = g[0], w1 = g[1], w2 = g[2], w3 = g[3];
    int bf;
    if(w0==0x3F803F80u && w1==0x3F803F80u && w2==0x3F803F80u && w3==0x3F803F80u) bf = 1;
    else if(w0==0x3F800000u && w1==0x3F800000u && w2==0x3F800000u && w3==0x3F800000u) bf = 0;
    else bf = 1;
    flag[0] = bf;
  }
  if(threadIdx.x < E_ && blockIdx.x == 0) cnt[threadIdx.x] = 0;
}

// ---------------- RMSNorm -> bf16 out (+ optional f32 copy for router) ----------------
__global__ __launch_bounds__(256) void k_rms(const void* __restrict__ X, const void* __restrict__ g,
                                             bf16* __restrict__ outb, float* __restrict__ outf,
                                             const int* __restrict__ flag, int xdyn){
  int isbf = flag[0]; int xb = xdyn ? isbf : 0;
  int t = blockIdx.x; int tid = threadIdx.x;
  float v[4]; float ss = 0.f;
  #pragma unroll
  for(int i=0;i<4;i++){ v[i] = dload(X, (size_t)t*D_ + tid + i*256, xb); ss += v[i]*v[i]; }
  __shared__ float red[256];
  red[tid] = ss; __syncthreads();
  for(int st=128; st>0; st>>=1){ if(tid<st) red[tid] += red[tid+st]; __syncthreads(); }
  float r = rsqrtf(red[0]*(1.f/(float)D_) + 1e-5f);
  #pragma unroll
  for(int i=0;i<4;i++){
    int d = tid + i*256;
    float val = v[i]*r*dload(g, d, isbf);
    outb[(size_t)t*D_ + d] = f2b(val);
    if(outf) outf[(size_t)t*D_ + d] = val;
  }
}

// =====================================================================
// MFMA GEMM, BM=128 BN=64 BK=32, 4 waves, double-buffered LDS + reg prefetch,
// ONE barrier per K-step. A bf16, B runtime-dtype. XOR k-block swizzle.
// Expert mode (cnt != nullptr): grid = (E, tiles), blockIdx.x = expert ->
// linear_id % 8 == expert -> all blocks of an expert on one XCD (weights L2-resident).
// AMAP: 0 = base+rloc, 2 = gather list>>1
// OMODE: 1 f32+resid, 2 bf16 scatter via list, 3 f32 accumulate, 4 bf16 store
// =====================================================================
#define ASTRIDE 40

static __device__ __forceinline__ f32x4 mfma16(short8v a, short8v b, f32x4 c){
  return __builtin_amdgcn_mfma_f32_16x16x32_bf16(a, b, c, 0, 0, 0);
}

template<int AMAP, int OMODE>
__global__ __launch_bounds__(256) void k_mgemm(
    const bf16* __restrict__ A, const void* __restrict__ Bw, void* __restrict__ Cout,
    const void* __restrict__ resid,
    int M, int N, int K, int ldc,
    const int* __restrict__ cnt, const int* __restrict__ offs, const int* __restrict__ list,
    const int* __restrict__ flag)
{
  int isbf = flag[0];
  int e, ct, rt;
  int base = 0; size_t eoff = 0;
  if(cnt){
    e = blockIdx.x;                 // expert = XCD affinity key
    int nc = (N+63)>>6;
    ct = blockIdx.y % nc; rt = blockIdx.y / nc;
    M = cnt[e]; if(M<0) M=0; if(M>NT_) M=NT_;
    base = offs[e];
    eoff = (size_t)e*(size_t)K*(size_t)N;
  } else {
    e = 0; ct = blockIdx.x; rt = blockIdx.y;
  }
  int m0 = rt*128; if(m0 >= M) return;
  int n0 = ct*64;

  __shared__ short As[2][128*ASTRIDE];
  __shared__ short Bs[2][64*ASTRIDE];
  __shared__ int rowA[128];

  int tid = threadIdx.x;
  int w = tid>>6, l = tid&63, lr = l&15, lg = l>>4;

  if(tid < 128){
    int rloc = m0 + tid;
    int ar = -1;
    if(rloc < M) ar = (AMAP==2) ? (list[e*NT_ + rloc]>>1) : (base + rloc);
    rowA[tid] = ar;
  }
  __syncthreads();

  int srow = tid>>1, skh = (tid&1)*16;
  int keya = (srow>>4)&3, kb0 = skh>>3;
  int bk = tid>>3, bnc = (tid&7)*8;
  int keyb = ((tid&7)>>1)&3;
  int bcol = (((bk>>3)^keyb)<<3) + (bk&7);
  int arow = rowA[srow];

  short8v rA0, rA1, rB;

  auto loadAB = [&](int kt){
    int k0 = kt*32;
    { // A (bf16)
      short tmp[16];
      if(arow >= 0 && k0+skh+16 <= K){
        const short4v* src = (const short4v*)(A + (size_t)arow*K + k0 + skh);
        #pragma unroll
        for(int c=0;c<4;c++) *(short4v*)&tmp[c*4] = src[c];
      } else {
        #pragma unroll
        for(int i=0;i<16;i++){
          int gk = k0+skh+i;
          short v = 0;
          if(arow>=0 && gk<K) v = *(const short*)&A[(size_t)arow*K+gk];
          tmp[i] = v;
        }
      }
      #pragma unroll
      for(int i=0;i<8;i++){ rA0[i]=tmp[i]; rA1[i]=tmp[8+i]; }
    }
    { // B (runtime dtype)
      int gk = k0 + bk;
      short tmp[8];
      if(gk < K && n0+bnc+8 <= N){
        size_t bb = eoff + (size_t)gk*N + n0 + bnc;
        if(isbf){
          const short4v* src = (const short4v*)((const bf16*)Bw + bb);
          *(short4v*)&tmp[0] = src[0];
          *(short4v*)&tmp[4] = src[1];
        } else {
          const f32x4* src = (const f32x4*)((const float*)Bw + bb);
          f32x4 f0 = src[0], f1 = src[1];
          #pragma unroll
          for(int i=0;i<4;i++){ tmp[i]=f2bs(f0[i]); tmp[4+i]=f2bs(f1[i]); }
        }
      } else {
        #pragma unroll
        for(int i=0;i<8;i++){
          int gn = n0+bnc+i;
          float v = 0.f;
          if(gk<K && gn<N) v = dload(Bw, eoff + (size_t)gk*N + gn, isbf);
          tmp[i] = f2bs(v);
        }
      }
      #pragma unroll
      for(int i=0;i<8;i++) rB[i]=tmp[i];
    }
  };
  auto writeAB = [&](int buf){
    *(short8v*)&As[buf][srow*ASTRIDE + ((kb0^keya)<<3)]     = rA0;
    *(short8v*)&As[buf][srow*ASTRIDE + (((kb0+1)^keya)<<3)] = rA1;
    #pragma unroll
    for(int i=0;i<8;i++) Bs[buf][(bnc+i)*ASTRIDE + bcol] = rB[i];
  };

  f32x4 acc[2][4] = {};
  int KT = (K+31)>>5;

  loadAB(0); writeAB(0);
  __syncthreads();
  int cur = 0;
  for(int kt=0; kt<KT; ++kt){
    bool more = (kt+1 < KT);
    if(more) loadAB(kt+1);
    short8v a[2], b[4];
    #pragma unroll
    for(int fi=0;fi<2;fi++)
      a[fi] = *(const short8v*)&As[cur][(w*32+fi*16+lr)*ASTRIDE + ((lg^((w*2+fi)&3))<<3)];
    #pragma unroll
    for(int fj=0;fj<4;fj++)
      b[fj] = *(const short8v*)&Bs[cur][(fj*16+lr)*ASTRIDE + ((lg^fj)<<3)];
    #pragma unroll
    for(int fi=0;fi<2;fi++)
      #pragma unroll
      for(int fj=0;fj<4;fj++)
        acc[fi][fj] = mfma16(a[fi], b[fj], acc[fi][fj]);
    if(more){ writeAB(cur^1); cur ^= 1; }
    __syncthreads();
  }

  #pragma unroll
  for(int fi=0;fi<2;fi++){
    #pragma unroll
    for(int r=0;r<4;r++){
      int rl = m0 + w*32 + fi*16 + lg*4 + r;
      if(rl >= M) continue;
      int orow;
      if(OMODE==2){ orow = list[e*NT_ + rl]; if(orow<0||orow>=2*NT_) continue; }
      else orow = base + rl;
      #pragma unroll
      for(int fj=0;fj<4;fj++){
        int gcol = n0 + fj*16 + lr;
        if(gcol >= N) continue;
        float v = acc[fi][fj][r];
        size_t o = (size_t)orow*ldc + gcol;
        if(OMODE==1)      ((float*)Cout)[o] = v + dload(resid, o, isbf);
        else if(OMODE==2) ((bf16*)Cout)[o] = f2b(v);
        else if(OMODE==3) ((float*)Cout)[o] = ((float*)Cout)[o] + v;
        else              ((bf16*)Cout)[o] = f2b(v);
      }
    }
  }
}

// =====================================================================
// Fused FFN1: out[base+r] = silu(A@W1) * (A@W3). Same geometry + XCD affinity.
// =====================================================================
template<int AMAP>
__global__ __launch_bounds__(256) void k_ffn1f(
    const bf16* __restrict__ A, const void* __restrict__ W1, const void* __restrict__ W3,
    bf16* __restrict__ Out, int M, int N, int K,
    const int* __restrict__ cnt, const int* __restrict__ offs, const int* __restrict__ list,
    const int* __restrict__ flag)
{
  int isbf = flag[0];
  int e, ct, rt;
  int base = 0; size_t eoff = 0;
  if(cnt){
    e = blockIdx.x;
    int nc = (N+63)>>6;
    ct = blockIdx.y % nc; rt = blockIdx.y / nc;
    M = cnt[e]; if(M<0) M=0; if(M>NT_) M=NT_;
    base = offs[e];
    eoff = (size_t)e*(size_t)K*(size_t)N;
  } else {
    e = 0; ct = blockIdx.x; rt = blockIdx.y;
  }
  int m0 = rt*128; if(m0 >= M) return;
  int n0 = ct*64;

  __shared__ short As[2][128*ASTRIDE];
  __shared__ short B1s[2][64*ASTRIDE];
  __shared__ short B3s[2][64*ASTRIDE];
  __shared__ int rowA[128];

  int tid = threadIdx.x;
  int w = tid>>6, l = tid&63, lr = l&15, lg = l>>4;

  if(tid < 128){
    int rloc = m0 + tid;
    int ar = -1;
    if(rloc < M) ar = (AMAP==2) ? (list[e*NT_ + rloc]>>1) : (base + rloc);
    rowA[tid] = ar;
  }
  __syncthreads();

  int srow = tid>>1, skh = (tid&1)*16;
  int keya = (srow>>4)&3, kb0 = skh>>3;
  int bk = tid>>3, bnc = (tid&7)*8;
  int keyb = ((tid&7)>>1)&3;
  int bcol = (((bk>>3)^keyb)<<3) + (bk&7);
  int arow = rowA[srow];

  short8v rA0, rA1, rB1, rB3;

  auto loadB = [&](const void* Bw, int kt, short8v& rB){
    int k0 = kt*32;
    int gk = k0 + bk;
    short tmp[8];
    if(gk < K && n0+bnc+8 <= N){
      size_t bb = eoff + (size_t)gk*N + n0 + bnc;
      if(isbf){
        const short4v* src = (const short4v*)((const bf16*)Bw + bb);
        *(short4v*)&tmp[0] = src[0];
        *(short4v*)&tmp[4] = src[1];
      } else {
        const f32x4* src = (const f32x4*)((const float*)Bw + bb);
        f32x4 f0 = src[0], f1 = src[1];
        #pragma unroll
        for(int i=0;i<4;i++){ tmp[i]=f2bs(f0[i]); tmp[4+i]=f2bs(f1[i]); }
      }
    } else {
      #pragma unroll
      for(int i=0;i<8;i++){
        int gn = n0+bnc+i;
        float v = 0.f;
        if(gk<K && gn<N) v = dload(Bw, eoff + (size_t)gk*N + gn, isbf);
        tmp[i] = f2bs(v);
      }
    }
    #pragma unroll
    for(int i=0;i<8;i++) rB[i]=tmp[i];
  };
  auto loadA = [&](int kt){
    int k0 = kt*32;
    short tmp[16];
    if(arow >= 0 && k0+skh+16 <= K){
      const short4v* src = (const short4v*)(A + (size_t)arow*K + k0 + skh);
      #pragma unroll
      for(int c=0;c<4;c++) *(short4v*)&tmp[c*4] = src[c];
    } else {
      #pragma unroll
      for(int i=0;i<16;i++){
        int gk = k0+skh+i;
        short v = 0;
        if(arow>=0 && gk<K) v = *(const short*)&A[(size_t)arow*K+gk];
        tmp[i] = v;
      }
    }
    #pragma unroll
    for(int i=0;i<8;i++){ rA0[i]=tmp[i]; rA1[i]=tmp[8+i]; }
  };
  auto writeAll = [&](int buf){
    *(short8v*)&As[buf][srow*ASTRIDE + ((kb0^keya)<<3)]     = rA0;
    *(short8v*)&As[buf][srow*ASTRIDE + (((kb0+1)^keya)<<3)] = rA1;
    #pragma unroll
    for(int i=0;i<8;i++){
      B1s[buf][(bnc+i)*ASTRIDE + bcol] = rB1[i];
      B3s[buf][(bnc+i)*ASTRIDE + bcol] = rB3[i];
    }
  };

  f32x4 a1[2][4] = {}, a3[2][4] = {};
  int KT = (K+31)>>5;

  loadA(0); loadB(W1, 0, rB1); loadB(W3, 0, rB3); writeAll(0);
  __syncthreads();
  int cur = 0;
  for(int kt=0; kt<KT; ++kt){
    bool more = (kt+1 < KT);
    if(more){ loadA(kt+1); loadB(W1, kt+1, rB1); loadB(W3, kt+1, rB3); }
    short8v a[2], b1[4], b3[4];
    #pragma unroll
    for(int fi=0;fi<2;fi++)
      a[fi] = *(const short8v*)&As[cur][(w*32+fi*16+lr)*ASTRIDE + ((lg^((w*2+fi)&3))<<3)];
    #pragma unroll
    for(int fj=0;fj<4;fj++){
      b1[fj] = *(const short8v*)&B1s[cur][(fj*16+lr)*ASTRIDE + ((lg^fj)<<3)];
      b3[fj] = *(const short8v*)&B3s[cur][(fj*16+lr)*ASTRIDE + ((lg^fj)<<3)];
    }
    #pragma unroll
    for(int fi=0;fi<2;fi++)
      #pragma unroll
      for(int fj=0;fj<4;fj++){
        a1[fi][fj] = mfma16(a[fi], b1[fj], a1[fi][fj]);
        a3[fi][fj] = mfma16(a[fi], b3[fj], a3[fi][fj]);
      }
    if(more){ writeAll(cur^1); cur ^= 1; }
    __syncthreads();
  }

  #pragma unroll
  for(int fi=0;fi<2;fi++){
    #pragma unroll
    for(int r=0;r<4;r++){
      int rl = m0 + w*32 + fi*16 + lg*4 + r;
      if(rl >= M) continue;
      int orow = base + rl;
      #pragma unroll
      for(int fj=0;fj<4;fj++){
        int gcol = n0 + fj*16 + lr;
        if(gcol >= N) continue;
        float sg = a1[fi][fj][r];
        float v = (sg/(1.f+__expf(-sg))) * a3[fi][fj][r];
        Out[(size_t)orow*N + gcol] = f2b(v);
      }
    }
  }
}

// ---------------- RoPE in-place on bf16 q and k ----------------
__global__ __launch_bounds__(256) void k_rope(bf16* __restrict__ ql, bf16* __restrict__ kl,
                                              const void* __restrict__ fc, const void* __restrict__ fs,
                                              const int* __restrict__ flag){
  int isbf = flag[0];
  int t = blockIdx.x; int s = t % S_;
  int tid = threadIdx.x;
  for(int p0 = tid; p0 < 512; p0 += 256){
    int h = p0>>5, p = p0&31;
    float c = dload(fc, s*32+p, isbf), sn = dload(fs, s*32+p, isbf);
    size_t o = (size_t)t*D_ + h*64 + 2*p;
    float xr = b2f(ql[o]), xi = b2f(ql[o+1]);
    ql[o]   = f2b(xr*c - xi*sn);
    ql[o+1] = f2b(xr*sn + xi*c);
  }
  if(tid < 128){
    int h = tid>>5, p = tid&31;
    float c = dload(fc, s*32+p, isbf), sn = dload(fs, s*32+p, isbf);
    size_t o = (size_t)t*256 + h*64 + 2*p;
    float xr = b2f(kl[o]), xi = b2f(kl[o+1]);
    kl[o]   = f2b(xr*c - xi*sn);
    kl[o+1] = f2b(xr*sn + xi*c);
  }
}

#define TST 72

__global__ __launch_bounds__(256) void k_attn(const bf16* __restrict__ Q, const bf16* __restrict__ Kg,
                                              const bf16* __restrict__ V, bf16* __restrict__ Out){
  int qt_ = (S_/64 - 1) - blockIdx.x;
  int h = blockIdx.y, b = blockIdx.z;
  int kvh = h>>2;
  const bf16* qb = Q + (size_t)b*S_*D_ + h*HD_;
  const bf16* kb = Kg + (size_t)b*S_*256 + kvh*HD_;
  const bf16* vb = V  + (size_t)b*S_*256 + kvh*HD_;
  __shared__ short Qs[64*TST];
  __shared__ short Ks[64*TST];
  __shared__ short Vt[64*TST];
  __shared__ short Ps[4][16*TST];
  int tid = threadIdx.x;
  int w = tid>>6, l = tid&63, lr = l&15, lg = l>>4;
  int sr = tid>>2, sc0 = (tid&3)*16;
  int vc = (((sr>>3)^(tid&3))<<3) + (sr&7);

  {
    const short8v* src = (const short8v*)(qb + (size_t)(qt_*64 + sr)*D_ + sc0);
    *(short8v*)&Qs[sr*TST + sc0]     = src[0];
    *(short8v*)&Qs[sr*TST + sc0 + 8] = src[1];
  }
  __syncthreads();
  short8v aQ0 = *(const short8v*)&Qs[(w*16+lr)*TST + lg*8];
  short8v aQ1 = *(const short8v*)&Qs[(w*16+lr)*TST + lg*8 + 32];

  float mreg[4], lreg[4];
  f32x4 accO[4] = {};
  #pragma unroll
  for(int r=0;r<4;r++){ mreg[r] = NEGBIG; lreg[r] = 0.f; }

  for(int kt=0; kt<=qt_; ++kt){
    __syncthreads();
    {
      const short8v* ksrc = (const short8v*)(kb + (size_t)(kt*64 + sr)*256 + sc0);
      *(short8v*)&Ks[sr*TST + sc0]     = ksrc[0];
      *(short8v*)&Ks[sr*TST + sc0 + 8] = ksrc[1];
      const short8v* vsrc = (const short8v*)(vb + (size_t)(kt*64 + sr)*256 + sc0);
      short8v v0 = vsrc[0], v1 = vsrc[1];
      #pragma unroll
      for(int i=0;i<8;i++){
        Vt[(sc0+i)*TST + vc]   = v0[i];
        Vt[(sc0+8+i)*TST + vc] = v1[i];
      }
    }
    __syncthreads();
    f32x4 s[4];
    #pragma unroll
    for(int fj=0; fj<4; fj++){
      short8v b0 = *(const short8v*)&Ks[(fj*16+lr)*TST + lg*8];
      short8v b1 = *(const short8v*)&Ks[(fj*16+lr)*TST + lg*8 + 32];
      f32x4 z = {};
      z = mfma16(aQ0, b0, z);
      z = mfma16(aQ1, b1, z);
      s[fj] = z;
    }
    #pragma unroll
    for(int fj=0; fj<4; fj++)
      #pragma unroll
      for(int r=0;r<4;r++){
        float v = s[fj][r]*0.125f;
        if(kt==qt_ && (fj*16+lr) > (w*16+lg*4+r)) v = NEGBIG;
        s[fj][r] = v;
      }
    float p[4][4], sc[4];
    #pragma unroll
    for(int r=0;r<4;r++){
      float mx = fmaxf(fmaxf(s[0][r],s[1][r]), fmaxf(s[2][r],s[3][r]));
      mx = fmaxf(mx, __shfl_xor(mx,1,64));
      mx = fmaxf(mx, __shfl_xor(mx,2,64));
      mx = fmaxf(mx, __shfl_xor(mx,4,64));
      mx = fmaxf(mx, __shfl_xor(mx,8,64));
      float mn = fmaxf(mreg[r], mx);
      sc[r] = __expf(mreg[r]-mn);
      float ps = 0.f;
      #pragma unroll
      for(int fj=0;fj<4;fj++){ float pv = __expf(s[fj][r]-mn); p[fj][r] = pv; ps += pv; }
      ps += __shfl_xor(ps,1,64); ps += __shfl_xor(ps,2,64);
      ps += __shfl_xor(ps,4,64); ps += __shfl_xor(ps,8,64);
      lreg[r] = lreg[r]*sc[r] + ps;
      mreg[r] = mn;
    }
    #pragma unroll
    for(int fj=0;fj<4;fj++)
      #pragma unroll
      for(int r=0;r<4;r++)
        accO[fj][r] *= sc[r];
    #pragma unroll
    for(int fj=0;fj<4;fj++)
      #pragma unroll
      for(int r=0;r<4;r++)
        Ps[w][(lg*4+r)*TST + fj*16+lr] = f2bs(p[fj][r]);
    short8v a0 = *(const short8v*)&Ps[w][lr*TST + lg*8];
    short8v a1 = *(const short8v*)&Ps[w][lr*TST + lg*8 + 32];
    #pragma unroll
    for(int fj=0;fj<4;fj++){
      int row = fj*16+lr;
      short8v b0 = *(const short8v*)&Vt[row*TST + ((lg^fj)<<3)];
      short8v b1 = *(const short8v*)&Vt[row*TST + (((lg^fj)+4)<<3)];
      accO[fj] = mfma16(a0, b0, accO[fj]);
      accO[fj] = mfma16(a1, b1, accO[fj]);
    }
  }
  #pragma unroll
  for(int r=0;r<4;r++){
    int qr = qt_*64 + w*16 + lg*4 + r;
    float inv = (lreg[r] > 0.f) ? 1.f/lreg[r] : 0.f;
    #pragma unroll
    for(int fj=0;fj<4;fj++)
      Out[((size_t)(b*S_+qr))*D_ + h*HD_ + fj*16+lr] = f2b(accO[fj][r]*inv);
  }
}

__global__ __launch_bounds__(64) void k_router(const float* __restrict__ X, const void* __restrict__ W,
                                               float* __restrict__ probs, float* __restrict__ p01,
                                               int* __restrict__ idx0buf, int* __restrict__ list,
                                               int* __restrict__ cnt, const int* __restrict__ flag){
  int isbf = flag[0];
  int t = blockIdx.x; int lane = threadIdx.x;
  float pe[8] = {};
  if(isbf){
    const bf16* Wb = (const bf16*)W;
    for(int d = lane; d < D_; d += 64){
      float xv = X[(size_t)t*D_ + d];
      #pragma unroll
      for(int e=0;e<8;e++) pe[e] += xv*b2f(Wb[(size_t)d*E_+e]);
    }
  } else {
    const float* Wf = (const float*)W;
    for(int d = lane; d < D_; d += 64){
      float xv = X[(size_t)t*D_ + d];
      #pragma unroll
      for(int e=0;e<8;e++) pe[e] += xv*Wf[(size_t)d*E_+e];
    }
  }
  for(int msk=1;msk<64;msk<<=1)
    #pragma unroll
    for(int e=0;e<8;e++) pe[e] += __shfl_xor(pe[e], msk, 64);
  if(lane == 0){
    float mx = pe[0];
    #pragma unroll
    for(int e=1;e<8;e++) mx = fmaxf(mx, pe[e]);
    float pr[8], sum = 0.f;
    #pragma unroll
    for(int e=0;e<8;e++){ pr[e] = __expf(pe[e]-mx); sum += pr[e]; }
    #pragma unroll
    for(int e=0;e<8;e++){ pr[e] /= sum; probs[t*8+e] = pr[e]; }
    int i0 = 0;
    #pragma unroll
    for(int e=1;e<8;e++) if(pe[e] > pe[i0]) i0 = e;
    int i1 = -1;
    #pragma unroll
    for(int e=0;e<8;e++){ if(e==i0) continue; if(i1<0 || pe[e] > pe[i1]) i1 = e; }
    p01[t*2]   = pr[i0];
    p01[t*2+1] = pr[i1];
    idx0buf[t] = i0;
    int pos = atomicAdd(&cnt[i0], 1);
    if(pos >= 0 && pos < NT_) list[i0*NT_ + pos] = t*2;
    pos     = atomicAdd(&cnt[i1], 1);
    if(pos >= 0 && pos < NT_) list[i1*NT_ + pos] = t*2 + 1;
  }
}

__global__ __launch_bounds__(256) void k_stats(const float* __restrict__ probs, const int* __restrict__ idx0buf,
                                               float* __restrict__ cnt0f, float* __restrict__ psum){
  int e = blockIdx.x; int tid = threadIdx.x;
  float sp = 0.f, sc = 0.f;
  for(int n = tid; n < NT_; n += 256){ sp += probs[n*8+e]; sc += (idx0buf[n]==e) ? 1.f : 0.f; }
  __shared__ float r1[256], r2[256];
  r1[tid] = sp; r2[tid] = sc; __syncthreads();
  for(int st=128; st>0; st>>=1){ if(tid<st){ r1[tid]+=r1[tid+st]; r2[tid]+=r2[tid+st]; } __syncthreads(); }
  if(tid==0){ psum[e] = r1[0]; cnt0f[e] = r2[0]; }
}

__global__ void k_finish(const float* __restrict__ cnt0f, const float* __restrict__ psum,
                         const int* __restrict__ cnt, int* __restrict__ offs,
                         bf16* __restrict__ auxb, float* __restrict__ auxf, const int* __restrict__ flag){
  if(threadIdx.x==0 && blockIdx.x==0){
    int o = 0;
    for(int e=0;e<8;e++){ offs[e] = o; int c = cnt[e]; if(c < 0) c = 0; if(c > NT_) c = NT_; o += c; }
    float aux = 0.f;
    for(int e=0;e<8;e++) aux += (cnt0f[e]*(1.f/(float)NT_))*(psum[e]*(1.f/(float)NT_));
    float v = aux*0.01f*8.f;
    if(flag[0]) auxb[0] = f2b(v); else auxf[0] = v;
  }
}

__global__ __launch_bounds__(256) void k_combine(const float* __restrict__ hbuf, const bf16* __restrict__ eosl,
                                                 const float* __restrict__ p01,
                                                 bf16* __restrict__ outb, float* __restrict__ outf,
                                                 const int* __restrict__ flag){
  int t = blockIdx.x; int tid = threadIdx.x;
  int isbf = flag[0];
  float p0 = p01[t*2], p1 = p01[t*2+1];
  #pragma unroll
  for(int i=0;i<4;i++){
    int d = tid + i*256;
    float v = hbuf[(size_t)t*D_ + d]
            + p0*b2f(eosl[((size_t)(t*2))*D_ + d])
            + p1*b2f(eosl[((size_t)(t*2+1))*D_ + d]);
    size_t o = (size_t)t*D_ + d;
    if(isbf) outb[o] = f2b(v); else outf[o] = v;
  }
}

// ---------------- workspace (bytes), peak ~63.3 MB ----------------
static const size_t O_HBUF = 0;
static const size_t O_XNB  = 16777216;
static const size_t O_QLIN = 25165824;
static const size_t O_KLIN = 33554432;
static const size_t O_VLIN = 35651584;
static const size_t O_AOUT = 37748736;
static const size_t O_XN2B = 16777216;
static const size_t O_XN2F = 25165824;
static const size_t O_HEXP = 46137344;
static const size_t O_SHH  = 57344000;
static const size_t O_EOSL = 16777216;
static const size_t O_PROBS= 62947328;
static const size_t O_P01  = 63078400;
static const size_t O_IDX0 = 63111168;
static const size_t O_LIST = 63127552;
static const size_t O_CNT  = 63258624;
static const size_t O_CNT0 = 63258656;
static const size_t O_PSUM = 63258688;
static const size_t O_OFFS = 63258720;
static const size_t O_FLAG = 63258752;

extern "C" void kernel_launch(void* const* d_in, const int* in_sizes, int n_in,
                              void* d_out, int out_size, void* d_ws, size_t ws_size,
                              hipStream_t stream){
  (void)in_sizes; (void)n_in; (void)out_size; (void)ws_size;
  char* ws = (char*)d_ws;
  float* hbuf = (float*)(ws + O_HBUF);
  bf16* xnb   = (bf16*)(ws + O_XNB);
  bf16* qlin  = (bf16*)(ws + O_QLIN);
  bf16* klin  = (bf16*)(ws + O_KLIN);
  bf16* vlin  = (bf16*)(ws + O_VLIN);
  bf16* aout  = (bf16*)(ws + O_AOUT);
  bf16* xn2b  = (bf16*)(ws + O_XN2B);
  float* xn2f = (float*)(ws + O_XN2F);
  bf16* hexp  = (bf16*)(ws + O_HEXP);
  bf16* shh   = (bf16*)(ws + O_SHH);
  bf16* eosl  = (bf16*)(ws + O_EOSL);
  float* probs=(float*)(ws + O_PROBS);
  float* p01 = (float*)(ws + O_P01);
  int*  idx0 = (int*)(ws + O_IDX0);
  int*  list = (int*)(ws + O_LIST);
  int*  cnt  = (int*)(ws + O_CNT);
  float* cnt0f=(float*)(ws + O_CNT0);
  float* psum= (float*)(ws + O_PSUM);
  int*  offs = (int*)(ws + O_OFFS);
  int*  flg  = (int*)(ws + O_FLAG);

  bf16* outb = (bf16*)d_out;
  float* outf = (float*)d_out;
  bf16* auxb = outb + (size_t)NT_*D_;
  float* auxf = outf + (size_t)NT_*D_;

  k_detect<<<1, 64, 0, stream>>>((const uint32_t*)d_in[14], flg, cnt);

  // ---- attention block ----
  k_rms<<<NT_, 256, 0, stream>>>(d_in[0], d_in[14], xnb, nullptr, flg, 1);

  k_mgemm<0,4><<<dim3(16,32), 256, 0, stream>>>(xnb, d_in[3], qlin, nullptr, NT_, D_, D_, D_, nullptr, nullptr, nullptr, flg);
  k_mgemm<0,4><<<dim3(4,32),  256, 0, stream>>>(xnb, d_in[4], klin, nullptr, NT_, 256, D_, 256, nullptr, nullptr, nullptr, flg);
  k_mgemm<0,4><<<dim3(4,32),  256, 0, stream>>>(xnb, d_in[5], vlin, nullptr, NT_, 256, D_, 256, nullptr, nullptr, nullptr, flg);

  k_rope<<<NT_, 256, 0, stream>>>(qlin, klin, d_in[1], d_in[2], flg);

  k_attn<<<dim3(S_/64, H_, B_), 256, 0, stream>>>(qlin, klin, vlin, aout);

  k_mgemm<0,1><<<dim3(16,32), 256, 0, stream>>>(aout, d_in[6], hbuf, d_in[0], NT_, D_, D_, D_, nullptr, nullptr, nullptr, flg);

  // ---- MoE block ----
  k_rms<<<NT_, 256, 0, stream>>>(hbuf, d_in[15], xn2b, xn2f, flg, 0);

  k_router<<<NT_, 64, 0, stream>>>(xn2f, d_in[7], probs, p01, idx0, list, cnt, flg);
  k_stats<<<E_, 256, 0, stream>>>(probs, idx0, cnt0f, psum);
  k_finish<<<1, 64, 0, stream>>>(cnt0f, psum, cnt, offs, auxb, auxf, flg);

  // fused ffn1 (+silu): expert (XCD-affinity grid: x=expert, y=tiles 11x32), shared (dense)
  k_ffn1f<2><<<dim3(E_, 11*32), 256, 0, stream>>>(xn2b, d_in[8], d_in[10], hexp, 0, HIDDEN_, D_, cnt, offs, list, flg);
  k_ffn1f<0><<<dim3(11,32),     256, 0, stream>>>(xn2b, d_in[11], d_in[13], shh, NT_, HIDDEN_, D_, nullptr, nullptr, nullptr, flg);

  // ffn2: expert scatter (XCD-affinity grid: x=expert, y=tiles 16x32), shared accumulate
  k_mgemm<0,2><<<dim3(E_, 16*32), 256, 0, stream>>>(hexp, d_in[9], eosl, nullptr, 0, D_, HIDDEN_, D_, cnt, offs, list, flg);
  k_mgemm<0,3><<<dim3(16,32),     256, 0, stream>>>(shh, d_in[12], hbuf, nullptr, NT_, D_, HIDDEN_, D_, nullptr, nullptr, nullptr, flg);

  k_combine<<<NT_, 256, 0, stream>>>(hbuf, eosl, p01, outb, outf, flg);
}